// Round 12
// baseline (345.141 us; speedup 1.0000x reference)
//
#include <hip/hip_runtime.h>
#include <hip/hip_bf16.h>

typedef __hip_bfloat16 bf16;

#define N_NODES 16384
#define D_IN    128
#define HID     64
#define HEADS   4
#define F1      256   // HEADS*HID
#define SEQ     128
#define SLOTS   64    // fixed CSR capacity per node (P(deg>64) ~ 1e-12 for this graph)

__device__ __forceinline__ float wave_sum(float v) {
    #pragma unroll
    for (int o = 32; o > 0; o >>= 1) v += __shfl_xor(v, o, 64);
    return v;
}
__device__ __forceinline__ float lrelu(float v) { return v > 0.f ? v : 0.2f * v; }
__device__ __forceinline__ float rdlane(float v, int l) {
    return __uint_as_float(__builtin_amdgcn_readlane(__float_as_uint(v), l));
}
__device__ __forceinline__ float bfu(unsigned short u) {
    return __uint_as_float((unsigned)u << 16);
}

// ---------------- D1: scatter + gemm1 (+PE, +logits) fused (R24) ----------------
// R24: occupancy-first retiling. Grid 2048 x 8 rows/block (2 rows/wave); W1 staged
// in 8 chunks of 16 K-rows (16 KB LDS, was 32 KB/4 chunks). Caps: LDS -> 10 blk/CU,
// waves -> 8 blk/CU; grid gives exactly 8/CU (R11 counters: Occ 30% at 4 blk/CU,
// VALUBusy 40% -> latency-starved, compute floor ~10us). Inter-block overlap now
// hides the staging barriers. W1 L2 re-staging 128->256 MB (~7us @35TB/s, hidden).
__global__ __launch_bounds__(256) void k_gemm1s(const float* __restrict__ x,
                                                const float* __restrict__ pe,
                                                const float* __restrict__ W1,
                                                const float* __restrict__ a_src1,
                                                const float* __restrict__ a_dst1,
                                                bf16* __restrict__ h,
                                                float* __restrict__ as1,
                                                float* __restrict__ ad1,
                                                const int* __restrict__ ei, int E, int Etot,
                                                int* __restrict__ cnt,
                                                int* __restrict__ esrc) {
    __shared__ float4 ws[1024];   // 16 K-rows x 64 float4 = 16 KB
    int tid = threadIdx.x, lane = tid & 63, wv = tid >> 6;

    // ---- phase 0: edge scatter (single-shot: 524288 threads >= Etot) ----
    {
        int e = blockIdx.x * 256 + tid;
        if (e < Etot) {
            int s, d;
            if (e < E) { s = ei[e]; d = ei[E + e]; }
            else       { s = e - E; d = s; }
            int pos = atomicAdd(&cnt[d], 1);
            if (pos < SLOTS) esrc[d * SLOTS + pos] = s;
        }
    }

    // ---- gemm phase: 2 rows/wave, W1 via 16 KB LDS chunks ----
    int base = blockIdx.x * 8;
    int j4 = lane * 4;
    float2 xr[2];
    #pragma unroll
    for (int i = 0; i < 2; i++) {
        int row = base + wv * 2 + i;
        float2 xa  = *(const float2*)(x  + (size_t)row * 128 + 2 * lane);
        float2 pea = *(const float2*)(pe + (size_t)(row & (SEQ - 1)) * 128 + 2 * lane);
        xr[i].x = xa.x * 11.313708499f + pea.x;
        xr[i].y = xa.y * 11.313708499f + pea.y;
    }
    float acc[2][4] = {};
    const float4* Wv = (const float4*)W1;   // Wv[k*64 + j] == W1[k*256 + j*4]
    for (int c = 0; c < 8; c++) {           // 8 chunks of 16 K-rows
        if (c > 0) __syncthreads();         // previous chunk fully consumed
        const float4* src = Wv + (size_t)c * 1024;
        #pragma unroll
        for (int i = 0; i < 4; i++) ws[i * 256 + tid] = src[i * 256 + tid];
        __syncthreads();
        #pragma unroll
        for (int lk2 = 0; lk2 < 8; lk2++) {
            int k2 = c * 8 + lk2;           // global float2-index (rdlane source)
            float4 w0 = ws[(2 * lk2) * 64 + lane];
            float4 w1 = ws[(2 * lk2 + 1) * 64 + lane];
            #pragma unroll
            for (int i = 0; i < 2; i++) {
                float a0 = rdlane(xr[i].x, k2);
                float a1 = rdlane(xr[i].y, k2);
                acc[i][0] += a0 * w0.x + a1 * w1.x;
                acc[i][1] += a0 * w0.y + a1 * w1.y;
                acc[i][2] += a0 * w0.z + a1 * w1.z;
                acc[i][3] += a0 * w0.w + a1 * w1.w;
            }
        }
    }
    float4 asv = *(const float4*)(a_src1 + j4);
    float4 adv = *(const float4*)(a_dst1 + j4);
    #pragma unroll
    for (int i = 0; i < 2; i++) {
        int row = base + wv * 2 + i;
        union { bf16 b[4]; ushort4 u; } cv;
        cv.b[0] = __float2bfloat16(acc[i][0]);
        cv.b[1] = __float2bfloat16(acc[i][1]);
        cv.b[2] = __float2bfloat16(acc[i][2]);
        cv.b[3] = __float2bfloat16(acc[i][3]);
        *(ushort4*)(h + (size_t)row * 256 + j4) = cv.u;
        float vs = acc[i][0] * asv.x + acc[i][1] * asv.y + acc[i][2] * asv.z + acc[i][3] * asv.w;
        float vd = acc[i][0] * adv.x + acc[i][1] * adv.y + acc[i][2] * adv.z + acc[i][3] * adv.w;
        #pragma unroll
        for (int o = 1; o < 16; o <<= 1) {
            vs += __shfl_xor(vs, o);
            vd += __shfl_xor(vd, o);
        }
        if ((lane & 15) == 0) {
            as1[row * 4 + (lane >> 4)] = vs;
            ad1[row * 4 + (lane >> 4)] = vd;
        }
    }
}

// ---------------- D2: fused softmax + agg1 + gemm2 (R23 known-good: transposed gather) ----------------
// 4096 blocks x 4 nodes; wave = head. Phase B lane = channel: per edge one coalesced
// 128B wave-load + cvt + FMA; no unpack shifts, no cross-lane reduce, full-wave
// epilogue. Phase A packs (s, t*inv) int2 in LDS; phase B 2-deep pipelined.
// NOTE (kernel law, R11/R13): TLP-bound — VGPR must stay < 64.
__global__ __launch_bounds__(256) void k_agg1_gemm2(
        const int* __restrict__ cnt, const int* __restrict__ esrc,
        const float* __restrict__ as1, const float* __restrict__ ad1,
        const bf16* __restrict__ h,
        const float* __restrict__ b1,
        const float* __restrict__ W2,
        const float* __restrict__ a_src2, const float* __restrict__ a_dst2,
        bf16* __restrict__ h2, float* __restrict__ as2, float* __restrict__ ad2) {
    __shared__ float hs[4][256];
    __shared__ int2  sts[16][64];   // (s, t*inv) per (node it, head wv); gemm2 aliases as part
    int tid = threadIdx.x, lane = tid & 63, wv = tid >> 6;
    int dbase = blockIdx.x * 4;

    int cv4 = cnt[dbase + (lane & 3)];               // 4 degrees, one load

    // ---- phase A: normalized per-head edge weights, packed with indices ----
    #pragma unroll
    for (int it = 0; it < 4; it++) {
        int d = dbase + it;
        int deg = min(__shfl(cv4, it), SLOTS);
        int s = esrc[(size_t)d * SLOTS + lane] & (N_NODES - 1);   // tail -> masked idx
        float av = as1[(size_t)s * 4 + wv];
        float adw = ad1[d * 4 + wv];
        float t = (lane < deg) ? __expf(lrelu(av + adw) - 40.f) : 0.f;
        float inv = 1.f / wave_sum(t);                // den > 0 (self-loop)
        int2 pr; pr.x = s; pr.y = __float_as_int(t * inv);
        sts[it * 4 + wv][lane] = pr;
    }
    // no barrier: each wave reads only sts rows it wrote itself

    // ---- phase B: lane = channel; per-edge coalesced 128B gathers, 2-deep pipeline ----
    const unsigned short* hb = (const unsigned short*)h + (size_t)wv * 64 + lane;
    float bb = b1[wv * 64 + lane];
    #pragma unroll 2
    for (int it = 0; it < 4; it++) {
        int deg = min(__shfl(cv4, it), SLOTS);
        const int4* row4 = (const int4*)sts[it * 4 + wv];   // (s0,t0,s1,t1) per int4
        int nq = (deg + 3) >> 2;                            // quads of 4 edges; tails t=0
        float acc = 0.f;
        int4 A = row4[0];
        int4 B = row4[1];
        unsigned short e0 = hb[(size_t)A.x * 256];
        unsigned short e1 = hb[(size_t)A.z * 256];
        unsigned short e2 = hb[(size_t)B.x * 256];
        unsigned short e3 = hb[(size_t)B.z * 256];
        for (int q = 1; q < nq; q++) {
            int4 An = row4[2 * q];
            int4 Bn = row4[2 * q + 1];
            unsigned short f0 = hb[(size_t)An.x * 256];
            unsigned short f1 = hb[(size_t)An.z * 256];
            unsigned short f2 = hb[(size_t)Bn.x * 256];
            unsigned short f3 = hb[(size_t)Bn.z * 256];
            acc += bfu(e0) * __uint_as_float(A.y);
            acc += bfu(e1) * __uint_as_float(A.w);
            acc += bfu(e2) * __uint_as_float(B.y);
            acc += bfu(e3) * __uint_as_float(B.w);
            A = An; B = Bn; e0 = f0; e1 = f1; e2 = f2; e3 = f3;
        }
        acc += bfu(e0) * __uint_as_float(A.y);
        acc += bfu(e1) * __uint_as_float(A.w);
        acc += bfu(e2) * __uint_as_float(B.y);
        acc += bfu(e3) * __uint_as_float(B.w);
        float v = acc + bb;
        hs[it][wv * 64 + lane] = v > 0.f ? v : (__expf(v) - 1.f);   // elu, all 64 lanes
    }
    __syncthreads();   // hs complete; sts dead from here -> reuse as part

    float* part = (float*)sts;   // 4 KB of the 8 KB sts buffer

    // ---- gemm2 on the 4 rows in LDS, K-split across the 4 waves ----
    {
        float acc2[4] = {0, 0, 0, 0};
        const int k4base = wv * 16;
        for (int kk = 0; kk < 16; kk++) {
            int k4 = k4base + kk;
            const float* wp = W2 + (size_t)k4 * 256 + lane;   // W2[(k4*4+q)*64 + lane]
            float w0 = wp[0], w1 = wp[64], w2 = wp[128], w3 = wp[192];
            #pragma unroll
            for (int r = 0; r < 4; r++) {
                float4 u = *(const float4*)&hs[r][k4 * 4];    // wave-uniform -> broadcast
                acc2[r] += u.x * w0 + u.y * w1 + u.z * w2 + u.w * w3;
            }
        }
        #pragma unroll
        for (int r = 0; r < 4; r++) part[(wv * 4 + r) * 64 + lane] = acc2[r];
    }
    __syncthreads();
    {
        int r = wv;                                   // one row per wave
        float a0 = part[(0 * 4 + r) * 64 + lane] + part[(1 * 4 + r) * 64 + lane]
                 + part[(2 * 4 + r) * 64 + lane] + part[(3 * 4 + r) * 64 + lane];
        float asj = a_src2[lane], adj = a_dst2[lane];
        int n0 = dbase + r;
        h2[(size_t)n0 * 64 + lane] = __float2bfloat16(a0);
        float va0 = wave_sum(a0 * asj);
        float vd0 = wave_sum(a0 * adj);
        if (lane == 0) {
            as2[n0] = va0; ad2[n0] = vd0;
        }
    }
}

// ---------------- D3: fused softmax + agg2 -> out (R23 known-good: transposed gather) ----------------
__global__ __launch_bounds__(256) void k_agg2(const int* __restrict__ cnt,
                                              const int* __restrict__ esrc,
                                              const float* __restrict__ as2,
                                              const float* __restrict__ ad2,
                                              const bf16* __restrict__ h2,
                                              const float* __restrict__ b2v,
                                              float* __restrict__ out) {
    __shared__ int2 sts2[4][64];
    int tid = threadIdx.x, lane = tid & 63, wv = tid >> 6;
    int d = blockIdx.x * 4 + wv;
    int deg = min(cnt[d], SLOTS);

    // phase A: per-edge normalized weights (lane = slot)
    int s = esrc[(size_t)d * SLOTS + lane] & (N_NODES - 1);
    float av = as2[s];
    float adw = ad2[d];
    float t = (lane < deg) ? __expf(lrelu(av + adw) - 40.f) : 0.f;
    float inv = 1.f / wave_sum(t);
    int2 pr; pr.x = s; pr.y = __float_as_int(t * inv);
    sts2[wv][lane] = pr;
    // no barrier: wave reads only its own row

    // phase B: lane = channel; 2-deep pipelined edge loop
    const unsigned short* hb = (const unsigned short*)h2 + lane;
    const int4* row4 = (const int4*)sts2[wv];
    int nq = (deg + 3) >> 2;
    float acc = 0.f;
    int4 A = row4[0];
    int4 B = row4[1];
    unsigned short e0 = hb[(size_t)A.x * 64];
    unsigned short e1 = hb[(size_t)A.z * 64];
    unsigned short e2 = hb[(size_t)B.x * 64];
    unsigned short e3 = hb[(size_t)B.z * 64];
    for (int q = 1; q < nq; q++) {
        int4 An = row4[2 * q];
        int4 Bn = row4[2 * q + 1];
        unsigned short f0 = hb[(size_t)An.x * 64];
        unsigned short f1 = hb[(size_t)An.z * 64];
        unsigned short f2 = hb[(size_t)Bn.x * 64];
        unsigned short f3 = hb[(size_t)Bn.z * 64];
        acc += bfu(e0) * __uint_as_float(A.y);
        acc += bfu(e1) * __uint_as_float(A.w);
        acc += bfu(e2) * __uint_as_float(B.y);
        acc += bfu(e3) * __uint_as_float(B.w);
        A = An; B = Bn; e0 = f0; e1 = f1; e2 = f2; e3 = f3;
    }
    acc += bfu(e0) * __uint_as_float(A.y);
    acc += bfu(e1) * __uint_as_float(A.w);
    acc += bfu(e2) * __uint_as_float(B.y);
    acc += bfu(e3) * __uint_as_float(B.w);
    out[(size_t)d * 64 + lane] = acc + b2v[lane];
}

extern "C" void kernel_launch(void* const* d_in, const int* in_sizes, int n_in,
                              void* d_out, int out_size, void* d_ws, size_t ws_size,
                              hipStream_t stream) {
    const float* x    = (const float*)d_in[0];
    const int*   ei   = (const int*)  d_in[1];
    const float* pe   = (const float*)d_in[2];
    const float* W1   = (const float*)d_in[3];
    const float* a_s1 = (const float*)d_in[4];
    const float* a_d1 = (const float*)d_in[5];
    const float* b1   = (const float*)d_in[6];
    const float* W2   = (const float*)d_in[7];
    const float* a_s2 = (const float*)d_in[8];
    const float* a_d2 = (const float*)d_in[9];
    const float* b2   = (const float*)d_in[10];

    const int E    = in_sizes[1] / 2;
    const int n    = N_NODES;
    const int Etot = E + n;

    // workspace carve-up (256B aligned) — footprint ~14.6 MB
    char* p = (char*)d_ws;
    auto alloc = [&](size_t bytes) -> void* {
        void* r = (void*)p;
        p += (bytes + 255) & ~(size_t)255;
        return r;
    };
    int*   cnt     = (int*)  alloc((size_t)n * 4);
    int*   esrc    = (int*)  alloc((size_t)n * SLOTS * 4);
    bf16*  h       = (bf16*) alloc((size_t)n * F1 * 2);
    float* as1     = (float*)alloc((size_t)n * HEADS * 4);
    float* ad1     = (float*)alloc((size_t)n * HEADS * 4);
    bf16*  h2      = (bf16*) alloc((size_t)n * HID * 2);
    float* as2     = (float*)alloc((size_t)n * 4);
    float* ad2     = (float*)alloc((size_t)n * 4);

    hipMemsetAsync(cnt, 0, (size_t)n * 4, stream);   // cnt zeroing

    k_gemm1s    <<<n / 8, 256, 0, stream>>>(x, pe, W1, a_s1, a_d1, h, as1, ad1,
                                            ei, E, Etot, cnt, esrc);
    k_agg1_gemm2<<<n / 4, 256, 0, stream>>>(cnt, esrc, as1, ad1, h, b1,
                                            W2, a_s2, a_d2, h2, as2, ad2);
    k_agg2      <<<n / 4, 256, 0, stream>>>(cnt, esrc, as2, ad2, h2, b2, (float*)d_out);
}

// Round 13
// 169.373 us; speedup vs baseline: 2.0378x; 2.0378x over previous
//
#include <hip/hip_runtime.h>
#include <hip/hip_bf16.h>

typedef __hip_bfloat16 bf16;

#define N_NODES 16384
#define D_IN    128
#define HID     64
#define HEADS   4
#define F1      256   // HEADS*HID
#define SEQ     128
#define SLOTS   64    // fixed CSR capacity per node (P(deg>64) ~ 1e-12 for this graph)

__device__ __forceinline__ float wave_sum(float v) {
    #pragma unroll
    for (int o = 32; o > 0; o >>= 1) v += __shfl_xor(v, o, 64);
    return v;
}
__device__ __forceinline__ float lrelu(float v) { return v > 0.f ? v : 0.2f * v; }
__device__ __forceinline__ float rdlane(float v, int l) {
    return __uint_as_float(__builtin_amdgcn_readlane(__float_as_uint(v), l));
}
__device__ __forceinline__ float bfu(unsigned short u) {
    return __uint_as_float((unsigned)u << 16);
}

// ---------------- D1: scatter + gemm1 (+PE, +logits) fused (R25) ----------------
// R25 = R22's EXACT staging structure (4 chunks x 32 K-rows = 32 KB LDS, proven
// VGPR 44) with only the tiling changed: 8 rows/block (2 rows/wave), grid 2048.
// KERNEL LAW (R12 post-mortem): any retile of this kernel MUST pin registers via
// __launch_bounds__ 2nd arg — the default let the scheduler balloon to VGPR 256
// and spill 600 MB of scratch (R24, 228us). (256,5): 5 waves/EU -> VGPR cap ~102
// (ample vs ~40 logical need), LDS caps 5 blk/CU, grid supplies 8 -> occupancy
// target ~62% theoretical (was grid-capped 50%, measured 30%).
__global__ __launch_bounds__(256, 5) void k_gemm1s(const float* __restrict__ x,
                                                   const float* __restrict__ pe,
                                                   const float* __restrict__ W1,
                                                   const float* __restrict__ a_src1,
                                                   const float* __restrict__ a_dst1,
                                                   bf16* __restrict__ h,
                                                   float* __restrict__ as1,
                                                   float* __restrict__ ad1,
                                                   const int* __restrict__ ei, int E, int Etot,
                                                   int* __restrict__ cnt,
                                                   int* __restrict__ esrc) {
    __shared__ float4 ws[2048];   // 32 K-rows x 64 float4 = 32 KB
    int tid = threadIdx.x, lane = tid & 63, wv = tid >> 6;

    // ---- phase 0: edge scatter (single-shot: 524288 threads >= Etot) ----
    {
        int e = blockIdx.x * 256 + tid;
        if (e < Etot) {
            int s, d;
            if (e < E) { s = ei[e]; d = ei[E + e]; }
            else       { s = e - E; d = s; }
            int pos = atomicAdd(&cnt[d], 1);
            if (pos < SLOTS) esrc[d * SLOTS + pos] = s;
        }
    }

    // ---- gemm phase: 2 rows/wave, W1 via 32 KB LDS chunks (R22 staging) ----
    int base = blockIdx.x * 8;
    int j4 = lane * 4;
    float2 xr[2];
    #pragma unroll
    for (int i = 0; i < 2; i++) {
        int row = base + wv * 2 + i;
        float2 xa  = *(const float2*)(x  + (size_t)row * 128 + 2 * lane);
        float2 pea = *(const float2*)(pe + (size_t)(row & (SEQ - 1)) * 128 + 2 * lane);
        xr[i].x = xa.x * 11.313708499f + pea.x;
        xr[i].y = xa.y * 11.313708499f + pea.y;
    }
    float acc[2][4] = {};
    const float4* Wv = (const float4*)W1;   // Wv[k*64 + j] == W1[k*256 + j*4]
    for (int c = 0; c < 4; c++) {           // 4 chunks of 32 K-rows
        if (c > 0) __syncthreads();         // previous chunk fully consumed
        const float4* src = Wv + (size_t)c * 2048;
        #pragma unroll
        for (int i = 0; i < 8; i++) ws[i * 256 + tid] = src[i * 256 + tid];
        __syncthreads();
        #pragma unroll 4
        for (int lk2 = 0; lk2 < 16; lk2++) {
            int k2 = c * 16 + lk2;          // global float2-index (rdlane source)
            float4 w0 = ws[(2 * lk2) * 64 + lane];
            float4 w1 = ws[(2 * lk2 + 1) * 64 + lane];
            #pragma unroll
            for (int i = 0; i < 2; i++) {
                float a0 = rdlane(xr[i].x, k2);
                float a1 = rdlane(xr[i].y, k2);
                acc[i][0] += a0 * w0.x + a1 * w1.x;
                acc[i][1] += a0 * w0.y + a1 * w1.y;
                acc[i][2] += a0 * w0.z + a1 * w1.z;
                acc[i][3] += a0 * w0.w + a1 * w1.w;
            }
        }
    }
    float4 asv = *(const float4*)(a_src1 + j4);
    float4 adv = *(const float4*)(a_dst1 + j4);
    #pragma unroll
    for (int i = 0; i < 2; i++) {
        int row = base + wv * 2 + i;
        union { bf16 b[4]; ushort4 u; } cv;
        cv.b[0] = __float2bfloat16(acc[i][0]);
        cv.b[1] = __float2bfloat16(acc[i][1]);
        cv.b[2] = __float2bfloat16(acc[i][2]);
        cv.b[3] = __float2bfloat16(acc[i][3]);
        *(ushort4*)(h + (size_t)row * 256 + j4) = cv.u;
        float vs = acc[i][0] * asv.x + acc[i][1] * asv.y + acc[i][2] * asv.z + acc[i][3] * asv.w;
        float vd = acc[i][0] * adv.x + acc[i][1] * adv.y + acc[i][2] * adv.z + acc[i][3] * adv.w;
        #pragma unroll
        for (int o = 1; o < 16; o <<= 1) {
            vs += __shfl_xor(vs, o);
            vd += __shfl_xor(vd, o);
        }
        if ((lane & 15) == 0) {
            as1[row * 4 + (lane >> 4)] = vs;
            ad1[row * 4 + (lane >> 4)] = vd;
        }
    }
}

// ---------------- D2: fused softmax + agg1 + gemm2 (R23 known-good: transposed gather) ----------------
// 4096 blocks x 4 nodes; wave = head. Phase B lane = channel: per edge one coalesced
// 128B wave-load + cvt + FMA; no unpack shifts, no cross-lane reduce, full-wave
// epilogue. Phase A packs (s, t*inv) int2 in LDS; phase B 2-deep pipelined.
// NOTE (kernel law, R11/R13): TLP-bound — VGPR must stay < 64.
__global__ __launch_bounds__(256) void k_agg1_gemm2(
        const int* __restrict__ cnt, const int* __restrict__ esrc,
        const float* __restrict__ as1, const float* __restrict__ ad1,
        const bf16* __restrict__ h,
        const float* __restrict__ b1,
        const float* __restrict__ W2,
        const float* __restrict__ a_src2, const float* __restrict__ a_dst2,
        bf16* __restrict__ h2, float* __restrict__ as2, float* __restrict__ ad2) {
    __shared__ float hs[4][256];
    __shared__ int2  sts[16][64];   // (s, t*inv) per (node it, head wv); gemm2 aliases as part
    int tid = threadIdx.x, lane = tid & 63, wv = tid >> 6;
    int dbase = blockIdx.x * 4;

    int cv4 = cnt[dbase + (lane & 3)];               // 4 degrees, one load

    // ---- phase A: normalized per-head edge weights, packed with indices ----
    #pragma unroll
    for (int it = 0; it < 4; it++) {
        int d = dbase + it;
        int deg = min(__shfl(cv4, it), SLOTS);
        int s = esrc[(size_t)d * SLOTS + lane] & (N_NODES - 1);   // tail -> masked idx
        float av = as1[(size_t)s * 4 + wv];
        float adw = ad1[d * 4 + wv];
        float t = (lane < deg) ? __expf(lrelu(av + adw) - 40.f) : 0.f;
        float inv = 1.f / wave_sum(t);                // den > 0 (self-loop)
        int2 pr; pr.x = s; pr.y = __float_as_int(t * inv);
        sts[it * 4 + wv][lane] = pr;
    }
    // no barrier: each wave reads only sts rows it wrote itself

    // ---- phase B: lane = channel; per-edge coalesced 128B gathers, 2-deep pipeline ----
    const unsigned short* hb = (const unsigned short*)h + (size_t)wv * 64 + lane;
    float bb = b1[wv * 64 + lane];
    #pragma unroll 2
    for (int it = 0; it < 4; it++) {
        int deg = min(__shfl(cv4, it), SLOTS);
        const int4* row4 = (const int4*)sts[it * 4 + wv];   // (s0,t0,s1,t1) per int4
        int nq = (deg + 3) >> 2;                            // quads of 4 edges; tails t=0
        float acc = 0.f;
        int4 A = row4[0];
        int4 B = row4[1];
        unsigned short e0 = hb[(size_t)A.x * 256];
        unsigned short e1 = hb[(size_t)A.z * 256];
        unsigned short e2 = hb[(size_t)B.x * 256];
        unsigned short e3 = hb[(size_t)B.z * 256];
        for (int q = 1; q < nq; q++) {
            int4 An = row4[2 * q];
            int4 Bn = row4[2 * q + 1];
            unsigned short f0 = hb[(size_t)An.x * 256];
            unsigned short f1 = hb[(size_t)An.z * 256];
            unsigned short f2 = hb[(size_t)Bn.x * 256];
            unsigned short f3 = hb[(size_t)Bn.z * 256];
            acc += bfu(e0) * __uint_as_float(A.y);
            acc += bfu(e1) * __uint_as_float(A.w);
            acc += bfu(e2) * __uint_as_float(B.y);
            acc += bfu(e3) * __uint_as_float(B.w);
            A = An; B = Bn; e0 = f0; e1 = f1; e2 = f2; e3 = f3;
        }
        acc += bfu(e0) * __uint_as_float(A.y);
        acc += bfu(e1) * __uint_as_float(A.w);
        acc += bfu(e2) * __uint_as_float(B.y);
        acc += bfu(e3) * __uint_as_float(B.w);
        float v = acc + bb;
        hs[it][wv * 64 + lane] = v > 0.f ? v : (__expf(v) - 1.f);   // elu, all 64 lanes
    }
    __syncthreads();   // hs complete; sts dead from here -> reuse as part

    float* part = (float*)sts;   // 4 KB of the 8 KB sts buffer

    // ---- gemm2 on the 4 rows in LDS, K-split across the 4 waves ----
    {
        float acc2[4] = {0, 0, 0, 0};
        const int k4base = wv * 16;
        for (int kk = 0; kk < 16; kk++) {
            int k4 = k4base + kk;
            const float* wp = W2 + (size_t)k4 * 256 + lane;   // W2[(k4*4+q)*64 + lane]
            float w0 = wp[0], w1 = wp[64], w2 = wp[128], w3 = wp[192];
            #pragma unroll
            for (int r = 0; r < 4; r++) {
                float4 u = *(const float4*)&hs[r][k4 * 4];    // wave-uniform -> broadcast
                acc2[r] += u.x * w0 + u.y * w1 + u.z * w2 + u.w * w3;
            }
        }
        #pragma unroll
        for (int r = 0; r < 4; r++) part[(wv * 4 + r) * 64 + lane] = acc2[r];
    }
    __syncthreads();
    {
        int r = wv;                                   // one row per wave
        float a0 = part[(0 * 4 + r) * 64 + lane] + part[(1 * 4 + r) * 64 + lane]
                 + part[(2 * 4 + r) * 64 + lane] + part[(3 * 4 + r) * 64 + lane];
        float asj = a_src2[lane], adj = a_dst2[lane];
        int n0 = dbase + r;
        h2[(size_t)n0 * 64 + lane] = __float2bfloat16(a0);
        float va0 = wave_sum(a0 * asj);
        float vd0 = wave_sum(a0 * adj);
        if (lane == 0) {
            as2[n0] = va0; ad2[n0] = vd0;
        }
    }
}

// ---------------- D3: fused softmax + agg2 -> out (R23 known-good: transposed gather) ----------------
__global__ __launch_bounds__(256) void k_agg2(const int* __restrict__ cnt,
                                              const int* __restrict__ esrc,
                                              const float* __restrict__ as2,
                                              const float* __restrict__ ad2,
                                              const bf16* __restrict__ h2,
                                              const float* __restrict__ b2v,
                                              float* __restrict__ out) {
    __shared__ int2 sts2[4][64];
    int tid = threadIdx.x, lane = tid & 63, wv = tid >> 6;
    int d = blockIdx.x * 4 + wv;
    int deg = min(cnt[d], SLOTS);

    // phase A: per-edge normalized weights (lane = slot)
    int s = esrc[(size_t)d * SLOTS + lane] & (N_NODES - 1);
    float av = as2[s];
    float adw = ad2[d];
    float t = (lane < deg) ? __expf(lrelu(av + adw) - 40.f) : 0.f;
    float inv = 1.f / wave_sum(t);
    int2 pr; pr.x = s; pr.y = __float_as_int(t * inv);
    sts2[wv][lane] = pr;
    // no barrier: wave reads only its own row

    // phase B: lane = channel; 2-deep pipelined edge loop
    const unsigned short* hb = (const unsigned short*)h2 + lane;
    const int4* row4 = (const int4*)sts2[wv];
    int nq = (deg + 3) >> 2;
    float acc = 0.f;
    int4 A = row4[0];
    int4 B = row4[1];
    unsigned short e0 = hb[(size_t)A.x * 64];
    unsigned short e1 = hb[(size_t)A.z * 64];
    unsigned short e2 = hb[(size_t)B.x * 64];
    unsigned short e3 = hb[(size_t)B.z * 64];
    for (int q = 1; q < nq; q++) {
        int4 An = row4[2 * q];
        int4 Bn = row4[2 * q + 1];
        unsigned short f0 = hb[(size_t)An.x * 64];
        unsigned short f1 = hb[(size_t)An.z * 64];
        unsigned short f2 = hb[(size_t)Bn.x * 64];
        unsigned short f3 = hb[(size_t)Bn.z * 64];
        acc += bfu(e0) * __uint_as_float(A.y);
        acc += bfu(e1) * __uint_as_float(A.w);
        acc += bfu(e2) * __uint_as_float(B.y);
        acc += bfu(e3) * __uint_as_float(B.w);
        A = An; B = Bn; e0 = f0; e1 = f1; e2 = f2; e3 = f3;
    }
    acc += bfu(e0) * __uint_as_float(A.y);
    acc += bfu(e1) * __uint_as_float(A.w);
    acc += bfu(e2) * __uint_as_float(B.y);
    acc += bfu(e3) * __uint_as_float(B.w);
    out[(size_t)d * 64 + lane] = acc + b2v[lane];
}

extern "C" void kernel_launch(void* const* d_in, const int* in_sizes, int n_in,
                              void* d_out, int out_size, void* d_ws, size_t ws_size,
                              hipStream_t stream) {
    const float* x    = (const float*)d_in[0];
    const int*   ei   = (const int*)  d_in[1];
    const float* pe   = (const float*)d_in[2];
    const float* W1   = (const float*)d_in[3];
    const float* a_s1 = (const float*)d_in[4];
    const float* a_d1 = (const float*)d_in[5];
    const float* b1   = (const float*)d_in[6];
    const float* W2   = (const float*)d_in[7];
    const float* a_s2 = (const float*)d_in[8];
    const float* a_d2 = (const float*)d_in[9];
    const float* b2   = (const float*)d_in[10];

    const int E    = in_sizes[1] / 2;
    const int n    = N_NODES;
    const int Etot = E + n;

    // workspace carve-up (256B aligned) — footprint ~14.6 MB
    char* p = (char*)d_ws;
    auto alloc = [&](size_t bytes) -> void* {
        void* r = (void*)p;
        p += (bytes + 255) & ~(size_t)255;
        return r;
    };
    int*   cnt     = (int*)  alloc((size_t)n * 4);
    int*   esrc    = (int*)  alloc((size_t)n * SLOTS * 4);
    bf16*  h       = (bf16*) alloc((size_t)n * F1 * 2);
    float* as1     = (float*)alloc((size_t)n * HEADS * 4);
    float* ad1     = (float*)alloc((size_t)n * HEADS * 4);
    bf16*  h2      = (bf16*) alloc((size_t)n * HID * 2);
    float* as2     = (float*)alloc((size_t)n * 4);
    float* ad2     = (float*)alloc((size_t)n * 4);

    hipMemsetAsync(cnt, 0, (size_t)n * 4, stream);   // cnt zeroing

    k_gemm1s    <<<n / 8, 256, 0, stream>>>(x, pe, W1, a_s1, a_d1, h, as1, ad1,
                                            ei, E, Etot, cnt, esrc);
    k_agg1_gemm2<<<n / 4, 256, 0, stream>>>(cnt, esrc, as1, ad1, h, b1,
                                            W2, a_s2, a_d2, h2, as2, ad2);
    k_agg2      <<<n / 4, 256, 0, stream>>>(cnt, esrc, as2, ad2, h2, b2, (float*)d_out);
}

// Round 15
// 159.873 us; speedup vs baseline: 2.1588x; 1.0594x over previous
//
#include <hip/hip_runtime.h>
#include <hip/hip_bf16.h>

typedef __hip_bfloat16 bf16;
typedef __attribute__((ext_vector_type(8))) short short8v;   // 8 bf16 in 4 VGPR
typedef __attribute__((ext_vector_type(4))) float f32x4;

#define N_NODES 16384
#define D_IN    128
#define HID     64
#define HEADS   4
#define F1      256   // HEADS*HID
#define SEQ     128
#define SLOTS   64    // fixed CSR capacity per node (P(deg>64) ~ 1e-12 for this graph)

__device__ __forceinline__ float wave_sum(float v) {
    #pragma unroll
    for (int o = 32; o > 0; o >>= 1) v += __shfl_xor(v, o, 64);
    return v;
}
__device__ __forceinline__ float lrelu(float v) { return v > 0.f ? v : 0.2f * v; }
__device__ __forceinline__ float bfu(unsigned short u) {
    return __uint_as_float((unsigned)u << 16);
}
__device__ __forceinline__ unsigned short f2b(float f) {   // fp32 -> bf16 RNE
    unsigned u = __float_as_uint(f);
    return (unsigned short)((u + 0x7fffu + ((u >> 16) & 1u)) >> 16);
}

// ---------------- D0: prep — W1 hi/lo bf16 split in MFMA B-frag order, g = W1·a, cnt=0 ----------------
// w1{hi,lo}[((n*4+ks)*64+l)*8+j] from W1[k][col], k = ks*32+(l>>4)*8+j, col = n*16+(l&15).
// gs/gd[k*4+hd] = sum_c W1[k][hd*64+c]*a_{src,dst}1[hd*64+c]  (fp32 — logits stay exact).
__global__ __launch_bounds__(256) void k_prep(const float* __restrict__ W1,
                                              const float* __restrict__ a_s1,
                                              const float* __restrict__ a_d1,
                                              unsigned short* __restrict__ w1hi,
                                              unsigned short* __restrict__ w1lo,
                                              float* __restrict__ gs,
                                              float* __restrict__ gd,
                                              int* __restrict__ cnt) {
    int gid = blockIdx.x * 256 + threadIdx.x;
    int j  = gid & 7;
    int l  = (gid >> 3) & 63;
    int ks = (gid >> 9) & 3;
    int n  = gid >> 11;
    int k   = ks * 32 + ((l >> 4) << 3) + j;
    int col = n * 16 + (l & 15);
    float w = W1[(size_t)k * 256 + col];
    unsigned short hi = f2b(w);
    w1hi[gid] = hi;
    w1lo[gid] = f2b(w - bfu(hi));
    if (gid < N_NODES) cnt[gid] = 0;
    if (gid < 512) {
        int kk = gid >> 2, hd = gid & 3;
        const float* wr = W1 + (size_t)kk * 256 + hd * 64;
        const float* as = a_s1 + hd * 64;
        const float* ad = a_d1 + hd * 64;
        float s = 0.f, d2 = 0.f;
        for (int c = 0; c < 64; c++) { float wv = wr[c]; s += wv * as[c]; d2 += wv * ad[c]; }
        gs[gid] = s; gd[gid] = d2;
    }
}

// ---------------- D1: scatter + MFMA gemm1 (+PE, +fp32 logits) (R27) ----------------
// R27 (fix of R26's precision failure): (1) logits as1/ad1 computed in FP32 from the
// pre-rounding x' values via the associativity refactor as1 = x'·(W1·a) — softmax
// exp-amplifies logit error, so logits must match the old fp32-gemm path (headroom
// was only 1.25 vs 1.44). (2) h computed via SPLIT bf16 MFMA: x'=ah+al, W1=bh+bl,
// acc = ah·bh + al·bh + ah·bl (al·bl ~2^-18 dropped) -> h error back to output-
// rounding-dominated, so layer-2 logits also keep old precision. k-permutation
// consistency (same map on A and B) makes the fragment k-layout correctness-neutral.
// KERNEL LAW (R12): launch_bounds 2nd arg REQUIRED — pins VGPR <= 128.
__global__ __launch_bounds__(256, 4) void k_gemm1m(const float* __restrict__ x,
                                                   const float* __restrict__ pe,
                                                   const unsigned short* __restrict__ w1hi,
                                                   const unsigned short* __restrict__ w1lo,
                                                   const float* __restrict__ gs,
                                                   const float* __restrict__ gd,
                                                   bf16* __restrict__ h,
                                                   float* __restrict__ as1,
                                                   float* __restrict__ ad1,
                                                   const int* __restrict__ ei, int E, int Etot,
                                                   int* __restrict__ cnt,
                                                   int* __restrict__ esrc) {
    int tid = threadIdx.x, lane = tid & 63, wv = tid >> 6;

    // ---- phase 0: edge scatter (grid-stride over 131072 threads) ----
    for (int e = blockIdx.x * 256 + tid; e < Etot; e += 131072) {
        int s, d;
        if (e < E) { s = ei[e]; d = ei[E + e]; }
        else       { s = e - E; d = s; }
        int pos = atomicAdd(&cnt[d], 1);
        if (pos < SLOTS) esrc[d * SLOTS + pos] = s;
    }

    // ---- gemm phase ----
    int strip = blockIdx.x * 2 + (wv >> 1);   // 16-row strip
    int nhalf = wv & 1;                       // which 128-col half
    int rowb = strip * 16;
    int r0 = lane & 15;                       // A row / C col within tile
    int kg = lane >> 4;                       // k-group (and C row-group)
    int kb = kg * 8;

    short8v afh[4], afl[4];                   // hi/lo A-frags, 4 K-steps
    f32x4 ls = {0.f, 0.f, 0.f, 0.f};          // fp32 logit partials (4 heads)
    f32x4 ld = {0.f, 0.f, 0.f, 0.f};
    #pragma unroll
    for (int ks = 0; ks < 4; ks++) {
        const float* xp = x  + (size_t)(rowb + r0) * 128 + ks * 32 + kb;
        const float* pp = pe + (size_t)((rowb + r0) & (SEQ - 1)) * 128 + ks * 32 + kb;
        float4 xa = *(const float4*)xp;
        float4 xb = *(const float4*)(xp + 4);
        float4 pa = *(const float4*)pp;
        float4 pb = *(const float4*)(pp + 4);
        float v[8];
        v[0] = xa.x * 11.313708499f + pa.x;
        v[1] = xa.y * 11.313708499f + pa.y;
        v[2] = xa.z * 11.313708499f + pa.z;
        v[3] = xa.w * 11.313708499f + pa.w;
        v[4] = xb.x * 11.313708499f + pb.x;
        v[5] = xb.y * 11.313708499f + pb.y;
        v[6] = xb.z * 11.313708499f + pb.z;
        v[7] = xb.w * 11.313708499f + pb.w;
        short8v ah, al;
        #pragma unroll
        for (int j = 0; j < 8; j++) {
            unsigned short hi = f2b(v[j]);
            ah[j] = (short)hi;
            al[j] = (short)f2b(v[j] - bfu(hi));
        }
        afh[ks] = ah; afl[ks] = al;
        if (nhalf == 0) {                     // fp32 logits (one wave per strip)
            #pragma unroll
            for (int j = 0; j < 8; j++) {
                int k = ks * 32 + kb + j;
                float4 g4 = *(const float4*)(gs + k * 4);
                float4 h4 = *(const float4*)(gd + k * 4);
                ls.x += v[j] * g4.x; ls.y += v[j] * g4.y;
                ls.z += v[j] * g4.z; ls.w += v[j] * g4.w;
                ld.x += v[j] * h4.x; ld.y += v[j] * h4.y;
                ld.z += v[j] * h4.z; ld.w += v[j] * h4.w;
            }
        }
    }
    if (nhalf == 0) {                         // reduce over the 4 kg lane-groups
        #pragma unroll
        for (int o = 16; o < 64; o <<= 1) {
            ls.x += __shfl_xor(ls.x, o); ls.y += __shfl_xor(ls.y, o);
            ls.z += __shfl_xor(ls.z, o); ls.w += __shfl_xor(ls.w, o);
            ld.x += __shfl_xor(ld.x, o); ld.y += __shfl_xor(ld.y, o);
            ld.z += __shfl_xor(ld.z, o); ld.w += __shfl_xor(ld.w, o);
        }
        if (lane < 16) {
            int row = rowb + lane;
            *(float4*)(as1 + row * 4) = make_float4(ls.x, ls.y, ls.z, ls.w);
            *(float4*)(ad1 + row * 4) = make_float4(ld.x, ld.y, ld.z, ld.w);
        }
    }

    const short8v* wph = (const short8v*)w1hi;
    const short8v* wpl = (const short8v*)w1lo;
    unsigned short* hu = (unsigned short*)h;
    #pragma unroll
    for (int t = 0; t < 8; t++) {
        int n = nhalf * 8 + t;                // N-tile (16 cols)
        f32x4 acc = {0.f, 0.f, 0.f, 0.f};
        #pragma unroll
        for (int ks = 0; ks < 4; ks++) {
            short8v bh = wph[(n * 4 + ks) * 64 + lane];
            short8v bl = wpl[(n * 4 + ks) * 64 + lane];
            acc = __builtin_amdgcn_mfma_f32_16x16x32_bf16(afh[ks], bh, acc, 0, 0, 0);
            acc = __builtin_amdgcn_mfma_f32_16x16x32_bf16(afl[ks], bh, acc, 0, 0, 0);
            acc = __builtin_amdgcn_mfma_f32_16x16x32_bf16(afh[ks], bl, acc, 0, 0, 0);
        }
        #pragma unroll
        for (int r = 0; r < 4; r++)
            hu[(size_t)(rowb + kg * 4 + r) * 256 + n * 16 + r0] = f2b(acc[r]);
    }
}

// ---------------- D2: fused softmax + agg1 + gemm2 (R23 known-good: transposed gather) ----------------
// 4096 blocks x 4 nodes; wave = head. Phase B lane = channel: per edge one coalesced
// 128B wave-load + cvt + FMA. Phase A packs (s, t*inv) int2 in LDS; 2-deep pipelined.
// NOTE (kernel law, R11/R13): TLP-bound — VGPR must stay < 64.
__global__ __launch_bounds__(256) void k_agg1_gemm2(
        const int* __restrict__ cnt, const int* __restrict__ esrc,
        const float* __restrict__ as1, const float* __restrict__ ad1,
        const bf16* __restrict__ h,
        const float* __restrict__ b1,
        const float* __restrict__ W2,
        const float* __restrict__ a_src2, const float* __restrict__ a_dst2,
        bf16* __restrict__ h2, float* __restrict__ as2, float* __restrict__ ad2) {
    __shared__ float hs[4][256];
    __shared__ int2  sts[16][64];   // (s, t*inv) per (node it, head wv); gemm2 aliases as part
    int tid = threadIdx.x, lane = tid & 63, wv = tid >> 6;
    int dbase = blockIdx.x * 4;

    int cv4 = cnt[dbase + (lane & 3)];               // 4 degrees, one load

    // ---- phase A: normalized per-head edge weights, packed with indices ----
    #pragma unroll
    for (int it = 0; it < 4; it++) {
        int d = dbase + it;
        int deg = min(__shfl(cv4, it), SLOTS);
        int s = esrc[(size_t)d * SLOTS + lane] & (N_NODES - 1);   // tail -> masked idx
        float av = as1[(size_t)s * 4 + wv];
        float adw = ad1[d * 4 + wv];
        float t = (lane < deg) ? __expf(lrelu(av + adw) - 40.f) : 0.f;
        float inv = 1.f / wave_sum(t);                // den > 0 (self-loop)
        int2 pr; pr.x = s; pr.y = __float_as_int(t * inv);
        sts[it * 4 + wv][lane] = pr;
    }
    // no barrier: each wave reads only sts rows it wrote itself

    // ---- phase B: lane = channel; per-edge coalesced 128B gathers, 2-deep pipeline ----
    const unsigned short* hb = (const unsigned short*)h + (size_t)wv * 64 + lane;
    float bb = b1[wv * 64 + lane];
    #pragma unroll 2
    for (int it = 0; it < 4; it++) {
        int deg = min(__shfl(cv4, it), SLOTS);
        const int4* row4 = (const int4*)sts[it * 4 + wv];   // (s0,t0,s1,t1) per int4
        int nq = (deg + 3) >> 2;                            // quads of 4 edges; tails t=0
        float acc = 0.f;
        int4 A = row4[0];
        int4 B = row4[1];
        unsigned short e0 = hb[(size_t)A.x * 256];
        unsigned short e1 = hb[(size_t)A.z * 256];
        unsigned short e2 = hb[(size_t)B.x * 256];
        unsigned short e3 = hb[(size_t)B.z * 256];
        for (int q = 1; q < nq; q++) {
            int4 An = row4[2 * q];
            int4 Bn = row4[2 * q + 1];
            unsigned short f0 = hb[(size_t)An.x * 256];
            unsigned short f1 = hb[(size_t)An.z * 256];
            unsigned short f2 = hb[(size_t)Bn.x * 256];
            unsigned short f3 = hb[(size_t)Bn.z * 256];
            acc += bfu(e0) * __uint_as_float(A.y);
            acc += bfu(e1) * __uint_as_float(A.w);
            acc += bfu(e2) * __uint_as_float(B.y);
            acc += bfu(e3) * __uint_as_float(B.w);
            A = An; B = Bn; e0 = f0; e1 = f1; e2 = f2; e3 = f3;
        }
        acc += bfu(e0) * __uint_as_float(A.y);
        acc += bfu(e1) * __uint_as_float(A.w);
        acc += bfu(e2) * __uint_as_float(B.y);
        acc += bfu(e3) * __uint_as_float(B.w);
        float v = acc + bb;
        hs[it][wv * 64 + lane] = v > 0.f ? v : (__expf(v) - 1.f);   // elu, all 64 lanes
    }
    __syncthreads();   // hs complete; sts dead from here -> reuse as part

    float* part = (float*)sts;   // 4 KB of the 8 KB sts buffer

    // ---- gemm2 on the 4 rows in LDS, K-split across the 4 waves ----
    {
        float acc2[4] = {0, 0, 0, 0};
        const int k4base = wv * 16;
        for (int kk = 0; kk < 16; kk++) {
            int k4 = k4base + kk;
            const float* wp = W2 + (size_t)k4 * 256 + lane;   // W2[(k4*4+q)*64 + lane]
            float w0 = wp[0], w1 = wp[64], w2 = wp[128], w3 = wp[192];
            #pragma unroll
            for (int r = 0; r < 4; r++) {
                float4 u = *(const float4*)&hs[r][k4 * 4];    // wave-uniform -> broadcast
                acc2[r] += u.x * w0 + u.y * w1 + u.z * w2 + u.w * w3;
            }
        }
        #pragma unroll
        for (int r = 0; r < 4; r++) part[(wv * 4 + r) * 64 + lane] = acc2[r];
    }
    __syncthreads();
    {
        int r = wv;                                   // one row per wave
        float a0 = part[(0 * 4 + r) * 64 + lane] + part[(1 * 4 + r) * 64 + lane]
                 + part[(2 * 4 + r) * 64 + lane] + part[(3 * 4 + r) * 64 + lane];
        float asj = a_src2[lane], adj = a_dst2[lane];
        int n0 = dbase + r;
        h2[(size_t)n0 * 64 + lane] = __float2bfloat16(a0);
        float va0 = wave_sum(a0 * asj);
        float vd0 = wave_sum(a0 * adj);
        if (lane == 0) {
            as2[n0] = va0; ad2[n0] = vd0;
        }
    }
}

// ---------------- D3: fused softmax + agg2 -> out (R23 known-good: transposed gather) ----------------
__global__ __launch_bounds__(256) void k_agg2(const int* __restrict__ cnt,
                                              const int* __restrict__ esrc,
                                              const float* __restrict__ as2,
                                              const float* __restrict__ ad2,
                                              const bf16* __restrict__ h2,
                                              const float* __restrict__ b2v,
                                              float* __restrict__ out) {
    __shared__ int2 sts2[4][64];
    int tid = threadIdx.x, lane = tid & 63, wv = tid >> 6;
    int d = blockIdx.x * 4 + wv;
    int deg = min(cnt[d], SLOTS);

    // phase A: per-edge normalized weights (lane = slot)
    int s = esrc[(size_t)d * SLOTS + lane] & (N_NODES - 1);
    float av = as2[s];
    float adw = ad2[d];
    float t = (lane < deg) ? __expf(lrelu(av + adw) - 40.f) : 0.f;
    float inv = 1.f / wave_sum(t);
    int2 pr; pr.x = s; pr.y = __float_as_int(t * inv);
    sts2[wv][lane] = pr;
    // no barrier: wave reads only its own row

    // phase B: lane = channel; 2-deep pipelined edge loop
    const unsigned short* hb = (const unsigned short*)h2 + lane;
    const int4* row4 = (const int4*)sts2[wv];
    int nq = (deg + 3) >> 2;
    float acc = 0.f;
    int4 A = row4[0];
    int4 B = row4[1];
    unsigned short e0 = hb[(size_t)A.x * 64];
    unsigned short e1 = hb[(size_t)A.z * 64];
    unsigned short e2 = hb[(size_t)B.x * 64];
    unsigned short e3 = hb[(size_t)B.z * 64];
    for (int q = 1; q < nq; q++) {
        int4 An = row4[2 * q];
        int4 Bn = row4[2 * q + 1];
        unsigned short f0 = hb[(size_t)An.x * 64];
        unsigned short f1 = hb[(size_t)An.z * 64];
        unsigned short f2 = hb[(size_t)Bn.x * 64];
        unsigned short f3 = hb[(size_t)Bn.z * 64];
        acc += bfu(e0) * __uint_as_float(A.y);
        acc += bfu(e1) * __uint_as_float(A.w);
        acc += bfu(e2) * __uint_as_float(B.y);
        acc += bfu(e3) * __uint_as_float(B.w);
        A = An; B = Bn; e0 = f0; e1 = f1; e2 = f2; e3 = f3;
    }
    acc += bfu(e0) * __uint_as_float(A.y);
    acc += bfu(e1) * __uint_as_float(A.w);
    acc += bfu(e2) * __uint_as_float(B.y);
    acc += bfu(e3) * __uint_as_float(B.w);
    out[(size_t)d * 64 + lane] = acc + b2v[lane];
}

extern "C" void kernel_launch(void* const* d_in, const int* in_sizes, int n_in,
                              void* d_out, int out_size, void* d_ws, size_t ws_size,
                              hipStream_t stream) {
    const float* x    = (const float*)d_in[0];
    const int*   ei   = (const int*)  d_in[1];
    const float* pe   = (const float*)d_in[2];
    const float* W1   = (const float*)d_in[3];
    const float* a_s1 = (const float*)d_in[4];
    const float* a_d1 = (const float*)d_in[5];
    const float* b1   = (const float*)d_in[6];
    const float* W2   = (const float*)d_in[7];
    const float* a_s2 = (const float*)d_in[8];
    const float* a_d2 = (const float*)d_in[9];
    const float* b2   = (const float*)d_in[10];

    const int E    = in_sizes[1] / 2;
    const int n    = N_NODES;
    const int Etot = E + n;

    // workspace carve-up (256B aligned) — footprint ~14.8 MB
    char* p = (char*)d_ws;
    auto alloc = [&](size_t bytes) -> void* {
        void* r = (void*)p;
        p += (bytes + 255) & ~(size_t)255;
        return r;
    };
    int*   cnt     = (int*)  alloc((size_t)n * 4);
    int*   esrc    = (int*)  alloc((size_t)n * SLOTS * 4);
    bf16*  h       = (bf16*) alloc((size_t)n * F1 * 2);
    float* as1     = (float*)alloc((size_t)n * HEADS * 4);
    float* ad1     = (float*)alloc((size_t)n * HEADS * 4);
    bf16*  h2      = (bf16*) alloc((size_t)n * HID * 2);
    float* as2     = (float*)alloc((size_t)n * 4);
    float* ad2     = (float*)alloc((size_t)n * 4);
    unsigned short* w1hi = (unsigned short*)alloc((size_t)D_IN * F1 * 2);   // 64 KB
    unsigned short* w1lo = (unsigned short*)alloc((size_t)D_IN * F1 * 2);   // 64 KB
    float* gs      = (float*)alloc((size_t)D_IN * HEADS * 4);               // 2 KB
    float* gd      = (float*)alloc((size_t)D_IN * HEADS * 4);               // 2 KB

    k_prep      <<<128, 256, 0, stream>>>(W1, a_s1, a_d1, w1hi, w1lo, gs, gd, cnt);
    k_gemm1m    <<<n / 32, 256, 0, stream>>>(x, pe, w1hi, w1lo, gs, gd, h, as1, ad1,
                                             ei, E, Etot, cnt, esrc);
    k_agg1_gemm2<<<n / 4, 256, 0, stream>>>(cnt, esrc, as1, ad1, h, b1,
                                            W2, a_s2, a_d2, h2, as2, ad2);
    k_agg2      <<<n / 4, 256, 0, stream>>>(cnt, esrc, as2, ad2, h2, b2, (float*)d_out);
}

// Round 16
// 155.246 us; speedup vs baseline: 2.2232x; 1.0298x over previous
//
#include <hip/hip_runtime.h>
#include <hip/hip_bf16.h>

typedef __hip_bfloat16 bf16;
typedef __attribute__((ext_vector_type(8))) short short8v;   // 8 bf16 in 4 VGPR
typedef __attribute__((ext_vector_type(4))) float f32x4;

#define N_NODES 16384
#define D_IN    128
#define HID     64
#define HEADS   4
#define F1      256   // HEADS*HID
#define SEQ     128
#define SLOTS   64    // fixed CSR capacity per node (P(deg>64) ~ 1e-12 for this graph)

__device__ __forceinline__ float wave_sum(float v) {
    #pragma unroll
    for (int o = 32; o > 0; o >>= 1) v += __shfl_xor(v, o, 64);
    return v;
}
__device__ __forceinline__ float lrelu(float v) { return v > 0.f ? v : 0.2f * v; }
__device__ __forceinline__ float bfu(unsigned short u) {
    return __uint_as_float((unsigned)u << 16);
}
__device__ __forceinline__ unsigned short f2b(float f) {   // fp32 -> bf16 RNE
    unsigned u = __float_as_uint(f);
    return (unsigned short)((u + 0x7fffu + ((u >> 16) & 1u)) >> 16);
}

// ---------------- D0: prep — W1 hi/lo bf16 split in MFMA B-frag order, g = W1·a, cnt=0 ----------------
// (R27 known-good)
__global__ __launch_bounds__(256) void k_prep(const float* __restrict__ W1,
                                              const float* __restrict__ a_s1,
                                              const float* __restrict__ a_d1,
                                              unsigned short* __restrict__ w1hi,
                                              unsigned short* __restrict__ w1lo,
                                              float* __restrict__ gs,
                                              float* __restrict__ gd,
                                              int* __restrict__ cnt) {
    int gid = blockIdx.x * 256 + threadIdx.x;
    int j  = gid & 7;
    int l  = (gid >> 3) & 63;
    int ks = (gid >> 9) & 3;
    int n  = gid >> 11;
    int k   = ks * 32 + ((l >> 4) << 3) + j;
    int col = n * 16 + (l & 15);
    float w = W1[(size_t)k * 256 + col];
    unsigned short hi = f2b(w);
    w1hi[gid] = hi;
    w1lo[gid] = f2b(w - bfu(hi));
    if (gid < N_NODES) cnt[gid] = 0;
    if (gid < 512) {
        int kk = gid >> 2, hd = gid & 3;
        const float* wr = W1 + (size_t)kk * 256 + hd * 64;
        const float* as = a_s1 + hd * 64;
        const float* ad = a_d1 + hd * 64;
        float s = 0.f, d2 = 0.f;
        for (int c = 0; c < 64; c++) { float wv = wr[c]; s += wv * as[c]; d2 += wv * ad[c]; }
        gs[gid] = s; gd[gid] = d2;
    }
}

// ---------------- D1: scatter + MFMA gemm1 (+PE, +fp32 logits) (R27 known-good) ----------------
// Split bf16 MFMA for h (hi·hi + lo·hi + hi·lo); fp32 logits via as1 = x'·(W1·a).
// KERNEL LAW (R12): launch_bounds 2nd arg REQUIRED — pins VGPR <= 128.
__global__ __launch_bounds__(256, 4) void k_gemm1m(const float* __restrict__ x,
                                                   const float* __restrict__ pe,
                                                   const unsigned short* __restrict__ w1hi,
                                                   const unsigned short* __restrict__ w1lo,
                                                   const float* __restrict__ gs,
                                                   const float* __restrict__ gd,
                                                   bf16* __restrict__ h,
                                                   float* __restrict__ as1,
                                                   float* __restrict__ ad1,
                                                   const int* __restrict__ ei, int E, int Etot,
                                                   int* __restrict__ cnt,
                                                   int* __restrict__ esrc) {
    int tid = threadIdx.x, lane = tid & 63, wv = tid >> 6;

    // ---- phase 0: edge scatter (grid-stride over 131072 threads) ----
    for (int e = blockIdx.x * 256 + tid; e < Etot; e += 131072) {
        int s, d;
        if (e < E) { s = ei[e]; d = ei[E + e]; }
        else       { s = e - E; d = s; }
        int pos = atomicAdd(&cnt[d], 1);
        if (pos < SLOTS) esrc[d * SLOTS + pos] = s;
    }

    // ---- gemm phase ----
    int strip = blockIdx.x * 2 + (wv >> 1);   // 16-row strip
    int nhalf = wv & 1;                       // which 128-col half
    int rowb = strip * 16;
    int r0 = lane & 15;                       // A row / C col within tile
    int kg = lane >> 4;                       // k-group (and C row-group)
    int kb = kg * 8;

    short8v afh[4], afl[4];                   // hi/lo A-frags, 4 K-steps
    f32x4 ls = {0.f, 0.f, 0.f, 0.f};          // fp32 logit partials (4 heads)
    f32x4 ld = {0.f, 0.f, 0.f, 0.f};
    #pragma unroll
    for (int ks = 0; ks < 4; ks++) {
        const float* xp = x  + (size_t)(rowb + r0) * 128 + ks * 32 + kb;
        const float* pp = pe + (size_t)((rowb + r0) & (SEQ - 1)) * 128 + ks * 32 + kb;
        float4 xa = *(const float4*)xp;
        float4 xb = *(const float4*)(xp + 4);
        float4 pa = *(const float4*)pp;
        float4 pb = *(const float4*)(pp + 4);
        float v[8];
        v[0] = xa.x * 11.313708499f + pa.x;
        v[1] = xa.y * 11.313708499f + pa.y;
        v[2] = xa.z * 11.313708499f + pa.z;
        v[3] = xa.w * 11.313708499f + pa.w;
        v[4] = xb.x * 11.313708499f + pb.x;
        v[5] = xb.y * 11.313708499f + pb.y;
        v[6] = xb.z * 11.313708499f + pb.z;
        v[7] = xb.w * 11.313708499f + pb.w;
        short8v ah, al;
        #pragma unroll
        for (int j = 0; j < 8; j++) {
            unsigned short hi = f2b(v[j]);
            ah[j] = (short)hi;
            al[j] = (short)f2b(v[j] - bfu(hi));
        }
        afh[ks] = ah; afl[ks] = al;
        if (nhalf == 0) {                     // fp32 logits (one wave per strip)
            #pragma unroll
            for (int j = 0; j < 8; j++) {
                int k = ks * 32 + kb + j;
                float4 g4 = *(const float4*)(gs + k * 4);
                float4 h4 = *(const float4*)(gd + k * 4);
                ls.x += v[j] * g4.x; ls.y += v[j] * g4.y;
                ls.z += v[j] * g4.z; ls.w += v[j] * g4.w;
                ld.x += v[j] * h4.x; ld.y += v[j] * h4.y;
                ld.z += v[j] * h4.z; ld.w += v[j] * h4.w;
            }
        }
    }
    if (nhalf == 0) {                         // reduce over the 4 kg lane-groups
        #pragma unroll
        for (int o = 16; o < 64; o <<= 1) {
            ls.x += __shfl_xor(ls.x, o); ls.y += __shfl_xor(ls.y, o);
            ls.z += __shfl_xor(ls.z, o); ls.w += __shfl_xor(ls.w, o);
            ld.x += __shfl_xor(ld.x, o); ld.y += __shfl_xor(ld.y, o);
            ld.z += __shfl_xor(ld.z, o); ld.w += __shfl_xor(ld.w, o);
        }
        if (lane < 16) {
            int row = rowb + lane;
            *(float4*)(as1 + row * 4) = make_float4(ls.x, ls.y, ls.z, ls.w);
            *(float4*)(ad1 + row * 4) = make_float4(ld.x, ld.y, ld.z, ld.w);
        }
    }

    const short8v* wph = (const short8v*)w1hi;
    const short8v* wpl = (const short8v*)w1lo;
    unsigned short* hu = (unsigned short*)h;
    #pragma unroll
    for (int t = 0; t < 8; t++) {
        int n = nhalf * 8 + t;                // N-tile (16 cols)
        f32x4 acc = {0.f, 0.f, 0.f, 0.f};
        #pragma unroll
        for (int ks = 0; ks < 4; ks++) {
            short8v bh = wph[(n * 4 + ks) * 64 + lane];
            short8v bl = wpl[(n * 4 + ks) * 64 + lane];
            acc = __builtin_amdgcn_mfma_f32_16x16x32_bf16(afh[ks], bh, acc, 0, 0, 0);
            acc = __builtin_amdgcn_mfma_f32_16x16x32_bf16(afl[ks], bh, acc, 0, 0, 0);
            acc = __builtin_amdgcn_mfma_f32_16x16x32_bf16(afh[ks], bl, acc, 0, 0, 0);
        }
        #pragma unroll
        for (int r = 0; r < 4; r++)
            hu[(size_t)(rowb + kg * 4 + r) * 256 + n * 16 + r0] = f2b(acc[r]);
    }
}

// ---------------- D2: fused softmax + agg1 + gemm2 (R28: full-row gather) ----------------
// R28: phase B wave = NODE, lane = 4 channels (uint2 load). One 512B wave-load per
// edge covers the whole 256-ch h row (all 4 heads; head = lane>>4). Edge-visits
// drop 4x (1.1M -> 278K) -> wave-instruction count ~halves vs R23 (agg1 was
// VALUBusy 70% = VALU-throughput-bound). Each h row touched ONCE -> better L2
// locality. Epilogue = full-wave float4 LDS store. Phase A: wave = node computes
// all 4 heads (as1 gather becomes one float4 vector gather); still wave-private,
// still no barrier. Edge pairs via int4 (s0,t0,s1,t1) LDS reads, 2-deep pipeline.
// NOTE (kernel law, R11/R13): TLP-bound — VGPR must stay < 64.
__global__ __launch_bounds__(256) void k_agg1_gemm2(
        const int* __restrict__ cnt, const int* __restrict__ esrc,
        const float* __restrict__ as1, const float* __restrict__ ad1,
        const bf16* __restrict__ h,
        const float* __restrict__ b1,
        const float* __restrict__ W2,
        const float* __restrict__ a_src2, const float* __restrict__ a_dst2,
        bf16* __restrict__ h2, float* __restrict__ as2, float* __restrict__ ad2) {
    __shared__ float hs[4][256];
    __shared__ int2  st[4][4][64];   // [wave(node)][head][slot] = (s, t*inv); gemm2 aliases as part
    int tid = threadIdx.x, lane = tid & 63, wv = tid >> 6;
    int dbase = blockIdx.x * 4;
    int d = dbase + wv;                               // wave's node
    int deg = min(cnt[d], SLOTS);

    // ---- phase A: all 4 heads' normalized edge weights for the wave's node ----
    {
        int s = esrc[(size_t)d * SLOTS + lane] & (N_NODES - 1);   // tail -> masked idx
        float4 av = *(const float4*)(as1 + (size_t)s * 4);        // one 16B gather
        float4 dv = *(const float4*)(ad1 + (size_t)d * 4);        // uniform
        bool live = lane < deg;
        float t0 = live ? __expf(lrelu(av.x + dv.x) - 40.f) : 0.f;
        float t1 = live ? __expf(lrelu(av.y + dv.y) - 40.f) : 0.f;
        float t2 = live ? __expf(lrelu(av.z + dv.z) - 40.f) : 0.f;
        float t3 = live ? __expf(lrelu(av.w + dv.w) - 40.f) : 0.f;
        float i0 = 1.f / wave_sum(t0);                // den > 0 (self-loop)
        float i1 = 1.f / wave_sum(t1);
        float i2 = 1.f / wave_sum(t2);
        float i3 = 1.f / wave_sum(t3);
        int2 p0; p0.x = s; p0.y = __float_as_int(t0 * i0); st[wv][0][lane] = p0;
        int2 p1; p1.x = s; p1.y = __float_as_int(t1 * i1); st[wv][1][lane] = p1;
        int2 p2; p2.x = s; p2.y = __float_as_int(t2 * i2); st[wv][2][lane] = p2;
        int2 p3; p3.x = s; p3.y = __float_as_int(t3 * i3); st[wv][3][lane] = p3;
    }
    // no barrier: wave reads only st[wv] rows it wrote itself

    // ---- phase B: lane = 4 channels; one uint2 load per edge covers all heads ----
    {
        int hd = lane >> 4;                           // head owning channels 4*lane..+3
        const int4* stp4 = (const int4*)st[wv][hd];   // (s0,t0,s1,t1) per edge pair
        const uint2* hb = (const uint2*)h;            // row s = 64 uint2
        float a0 = 0.f, a1 = 0.f, a2 = 0.f, a3 = 0.f;
        int np = (deg + 1) >> 1;                      // edge pairs; tails t=0
        int4 P = stp4[0];
        uint2 u0 = hb[(size_t)P.x * 64 + lane];
        uint2 u1 = hb[(size_t)P.z * 64 + lane];
        for (int q = 1; q < np; q++) {
            int4 Pn = stp4[q];
            uint2 v0 = hb[(size_t)Pn.x * 64 + lane];
            uint2 v1 = hb[(size_t)Pn.z * 64 + lane];
            float ta = __uint_as_float(P.y), tb = __uint_as_float(P.w);
            a0 += __uint_as_float(u0.x << 16) * ta;
            a1 += __uint_as_float(u0.x & 0xffff0000u) * ta;
            a2 += __uint_as_float(u0.y << 16) * ta;
            a3 += __uint_as_float(u0.y & 0xffff0000u) * ta;
            a0 += __uint_as_float(u1.x << 16) * tb;
            a1 += __uint_as_float(u1.x & 0xffff0000u) * tb;
            a2 += __uint_as_float(u1.y << 16) * tb;
            a3 += __uint_as_float(u1.y & 0xffff0000u) * tb;
            P = Pn; u0 = v0; u1 = v1;
        }
        float ta = __uint_as_float(P.y), tb = __uint_as_float(P.w);
        a0 += __uint_as_float(u0.x << 16) * ta;
        a1 += __uint_as_float(u0.x & 0xffff0000u) * ta;
        a2 += __uint_as_float(u0.y << 16) * ta;
        a3 += __uint_as_float(u0.y & 0xffff0000u) * ta;
        a0 += __uint_as_float(u1.x << 16) * tb;
        a1 += __uint_as_float(u1.x & 0xffff0000u) * tb;
        a2 += __uint_as_float(u1.y << 16) * tb;
        a3 += __uint_as_float(u1.y & 0xffff0000u) * tb;

        float4 bb = *(const float4*)(b1 + lane * 4);
        float o0 = a0 + bb.x, o1 = a1 + bb.y, o2 = a2 + bb.z, o3 = a3 + bb.w;
        o0 = o0 > 0.f ? o0 : (__expf(o0) - 1.f);      // elu
        o1 = o1 > 0.f ? o1 : (__expf(o1) - 1.f);
        o2 = o2 > 0.f ? o2 : (__expf(o2) - 1.f);
        o3 = o3 > 0.f ? o3 : (__expf(o3) - 1.f);
        *(float4*)&hs[wv][lane * 4] = make_float4(o0, o1, o2, o3);   // full-wave store
    }
    __syncthreads();   // hs complete; st dead from here -> reuse as part

    float* part = (float*)st;   // 4 KB of the 8 KB st buffer

    // ---- gemm2 on the 4 rows in LDS, K-split across the 4 waves ----
    {
        float acc2[4] = {0, 0, 0, 0};
        const int k4base = wv * 16;
        for (int kk = 0; kk < 16; kk++) {
            int k4 = k4base + kk;
            const float* wp = W2 + (size_t)k4 * 256 + lane;   // W2[(k4*4+q)*64 + lane]
            float w0 = wp[0], w1 = wp[64], w2 = wp[128], w3 = wp[192];
            #pragma unroll
            for (int r = 0; r < 4; r++) {
                float4 u = *(const float4*)&hs[r][k4 * 4];    // wave-uniform -> broadcast
                acc2[r] += u.x * w0 + u.y * w1 + u.z * w2 + u.w * w3;
            }
        }
        #pragma unroll
        for (int r = 0; r < 4; r++) part[(wv * 4 + r) * 64 + lane] = acc2[r];
    }
    __syncthreads();
    {
        int r = wv;                                   // one row per wave
        float a0 = part[(0 * 4 + r) * 64 + lane] + part[(1 * 4 + r) * 64 + lane]
                 + part[(2 * 4 + r) * 64 + lane] + part[(3 * 4 + r) * 64 + lane];
        float asj = a_src2[lane], adj = a_dst2[lane];
        int n0 = dbase + r;
        h2[(size_t)n0 * 64 + lane] = __float2bfloat16(a0);
        float va0 = wave_sum(a0 * asj);
        float vd0 = wave_sum(a0 * adj);
        if (lane == 0) {
            as2[n0] = va0; ad2[n0] = vd0;
        }
    }
}

// ---------------- D3: fused softmax + agg2 -> out (R23 known-good: transposed gather) ----------------
__global__ __launch_bounds__(256) void k_agg2(const int* __restrict__ cnt,
                                              const int* __restrict__ esrc,
                                              const float* __restrict__ as2,
                                              const float* __restrict__ ad2,
                                              const bf16* __restrict__ h2,
                                              const float* __restrict__ b2v,
                                              float* __restrict__ out) {
    __shared__ int2 sts2[4][64];
    int tid = threadIdx.x, lane = tid & 63, wv = tid >> 6;
    int d = blockIdx.x * 4 + wv;
    int deg = min(cnt[d], SLOTS);

    // phase A: per-edge normalized weights (lane = slot)
    int s = esrc[(size_t)d * SLOTS + lane] & (N_NODES - 1);
    float av = as2[s];
    float adw = ad2[d];
    float t = (lane < deg) ? __expf(lrelu(av + adw) - 40.f) : 0.f;
    float inv = 1.f / wave_sum(t);
    int2 pr; pr.x = s; pr.y = __float_as_int(t * inv);
    sts2[wv][lane] = pr;
    // no barrier: wave reads only its own row

    // phase B: lane = channel; 2-deep pipelined edge loop
    const unsigned short* hb = (const unsigned short*)h2 + lane;
    const int4* row4 = (const int4*)sts2[wv];
    int nq = (deg + 3) >> 2;
    float acc = 0.f;
    int4 A = row4[0];
    int4 B = row4[1];
    unsigned short e0 = hb[(size_t)A.x * 64];
    unsigned short e1 = hb[(size_t)A.z * 64];
    unsigned short e2 = hb[(size_t)B.x * 64];
    unsigned short e3 = hb[(size_t)B.z * 64];
    for (int q = 1; q < nq; q++) {
        int4 An = row4[2 * q];
        int4 Bn = row4[2 * q + 1];
        unsigned short f0 = hb[(size_t)An.x * 64];
        unsigned short f1 = hb[(size_t)An.z * 64];
        unsigned short f2 = hb[(size_t)Bn.x * 64];
        unsigned short f3 = hb[(size_t)Bn.z * 64];
        acc += bfu(e0) * __uint_as_float(A.y);
        acc += bfu(e1) * __uint_as_float(A.w);
        acc += bfu(e2) * __uint_as_float(B.y);
        acc += bfu(e3) * __uint_as_float(B.w);
        A = An; B = Bn; e0 = f0; e1 = f1; e2 = f2; e3 = f3;
    }
    acc += bfu(e0) * __uint_as_float(A.y);
    acc += bfu(e1) * __uint_as_float(A.w);
    acc += bfu(e2) * __uint_as_float(B.y);
    acc += bfu(e3) * __uint_as_float(B.w);
    out[(size_t)d * 64 + lane] = acc + b2v[lane];
}

extern "C" void kernel_launch(void* const* d_in, const int* in_sizes, int n_in,
                              void* d_out, int out_size, void* d_ws, size_t ws_size,
                              hipStream_t stream) {
    const float* x    = (const float*)d_in[0];
    const int*   ei   = (const int*)  d_in[1];
    const float* pe   = (const float*)d_in[2];
    const float* W1   = (const float*)d_in[3];
    const float* a_s1 = (const float*)d_in[4];
    const float* a_d1 = (const float*)d_in[5];
    const float* b1   = (const float*)d_in[6];
    const float* W2   = (const float*)d_in[7];
    const float* a_s2 = (const float*)d_in[8];
    const float* a_d2 = (const float*)d_in[9];
    const float* b2   = (const float*)d_in[10];

    const int E    = in_sizes[1] / 2;
    const int n    = N_NODES;
    const int Etot = E + n;

    // workspace carve-up (256B aligned) — footprint ~14.8 MB
    char* p = (char*)d_ws;
    auto alloc = [&](size_t bytes) -> void* {
        void* r = (void*)p;
        p += (bytes + 255) & ~(size_t)255;
        return r;
    };
    int*   cnt     = (int*)  alloc((size_t)n * 4);
    int*   esrc    = (int*)  alloc((size_t)n * SLOTS * 4);
    bf16*  h       = (bf16*) alloc((size_t)n * F1 * 2);
    float* as1     = (float*)alloc((size_t)n * HEADS * 4);
    float* ad1     = (float*)alloc((size_t)n * HEADS * 4);
    bf16*  h2      = (bf16*) alloc((size_t)n * HID * 2);
    float* as2     = (float*)alloc((size_t)n * 4);
    float* ad2     = (float*)alloc((size_t)n * 4);
    unsigned short* w1hi = (unsigned short*)alloc((size_t)D_IN * F1 * 2);   // 64 KB
    unsigned short* w1lo = (unsigned short*)alloc((size_t)D_IN * F1 * 2);   // 64 KB
    float* gs      = (float*)alloc((size_t)D_IN * HEADS * 4);               // 2 KB
    float* gd      = (float*)alloc((size_t)D_IN * HEADS * 4);               // 2 KB

    k_prep      <<<128, 256, 0, stream>>>(W1, a_s1, a_d1, w1hi, w1lo, gs, gd, cnt);
    k_gemm1m    <<<n / 32, 256, 0, stream>>>(x, pe, w1hi, w1lo, gs, gd, h, as1, ad1,
                                             ei, E, Etot, cnt, esrc);
    k_agg1_gemm2<<<n / 4, 256, 0, stream>>>(cnt, esrc, as1, ad1, h, b1,
                                            W2, a_s2, a_d2, h2, as2, ad2);
    k_agg2      <<<n / 4, 256, 0, stream>>>(cnt, esrc, as2, ad2, h2, b2, (float*)d_out);
}

// Round 17
// 154.834 us; speedup vs baseline: 2.2291x; 1.0027x over previous
//
#include <hip/hip_runtime.h>
#include <hip/hip_bf16.h>

typedef __hip_bfloat16 bf16;
typedef __attribute__((ext_vector_type(8))) short short8v;   // 8 bf16 in 4 VGPR
typedef __attribute__((ext_vector_type(4))) float f32x4;

#define N_NODES 16384
#define D_IN    128
#define HID     64
#define HEADS   4
#define F1      256   // HEADS*HID
#define SEQ     128
#define SLOTS   64    // fixed CSR capacity per node (P(deg>64) ~ 1e-12 for this graph)

__device__ __forceinline__ float wave_sum(float v) {
    #pragma unroll
    for (int o = 32; o > 0; o >>= 1) v += __shfl_xor(v, o, 64);
    return v;
}
__device__ __forceinline__ float lrelu(float v) { return v > 0.f ? v : 0.2f * v; }
__device__ __forceinline__ float bfu(unsigned short u) {
    return __uint_as_float((unsigned)u << 16);
}
__device__ __forceinline__ unsigned short f2b(float f) {   // fp32 -> bf16 RNE
    unsigned u = __float_as_uint(f);
    return (unsigned short)((u + 0x7fffu + ((u >> 16) & 1u)) >> 16);
}

// ---------------- D0: prep — W1 hi/lo bf16 split in MFMA B-frag order, g = W1·a, cnt=0 ----------------
// (R27 known-good)
__global__ __launch_bounds__(256) void k_prep(const float* __restrict__ W1,
                                              const float* __restrict__ a_s1,
                                              const float* __restrict__ a_d1,
                                              unsigned short* __restrict__ w1hi,
                                              unsigned short* __restrict__ w1lo,
                                              float* __restrict__ gs,
                                              float* __restrict__ gd,
                                              int* __restrict__ cnt) {
    int gid = blockIdx.x * 256 + threadIdx.x;
    int j  = gid & 7;
    int l  = (gid >> 3) & 63;
    int ks = (gid >> 9) & 3;
    int n  = gid >> 11;
    int k   = ks * 32 + ((l >> 4) << 3) + j;
    int col = n * 16 + (l & 15);
    float w = W1[(size_t)k * 256 + col];
    unsigned short hi = f2b(w);
    w1hi[gid] = hi;
    w1lo[gid] = f2b(w - bfu(hi));
    if (gid < N_NODES) cnt[gid] = 0;
    if (gid < 512) {
        int kk = gid >> 2, hd = gid & 3;
        const float* wr = W1 + (size_t)kk * 256 + hd * 64;
        const float* as = a_s1 + hd * 64;
        const float* ad = a_d1 + hd * 64;
        float s = 0.f, d2 = 0.f;
        for (int c = 0; c < 64; c++) { float wv = wr[c]; s += wv * as[c]; d2 += wv * ad[c]; }
        gs[gid] = s; gd[gid] = d2;
    }
}

// ---------------- D1: scatter + MFMA gemm1 (+PE, +fp32 logits) (R29: occupancy retile) ----------------
// R29: grid 512 -> 1024 (block = ONE 16-row strip, 4 waves x 4 N-tiles each, 48
// MFMA/wave). 2 -> 4 blocks/CU, 8 -> 16 waves/CU — same math, 2x latency hiding
// (the R22-25 lesson: this family is latency-starved, not compute-bound). A-row
// loads duplicate across the 4 waves (8 KB/block, L1-hot — cheap). Logits by wave 0.
// KERNEL LAW (R12): launch_bounds 2nd arg REQUIRED — pins VGPR <= 128.
__global__ __launch_bounds__(256, 4) void k_gemm1m(const float* __restrict__ x,
                                                   const float* __restrict__ pe,
                                                   const unsigned short* __restrict__ w1hi,
                                                   const unsigned short* __restrict__ w1lo,
                                                   const float* __restrict__ gs,
                                                   const float* __restrict__ gd,
                                                   bf16* __restrict__ h,
                                                   float* __restrict__ as1,
                                                   float* __restrict__ ad1,
                                                   const int* __restrict__ ei, int E, int Etot,
                                                   int* __restrict__ cnt,
                                                   int* __restrict__ esrc) {
    int tid = threadIdx.x, lane = tid & 63, wv = tid >> 6;

    // ---- phase 0: edge scatter (grid-stride over 262144 threads) ----
    for (int e = blockIdx.x * 256 + tid; e < Etot; e += 262144) {
        int s, d;
        if (e < E) { s = ei[e]; d = ei[E + e]; }
        else       { s = e - E; d = s; }
        int pos = atomicAdd(&cnt[d], 1);
        if (pos < SLOTS) esrc[d * SLOTS + pos] = s;
    }

    // ---- gemm phase: one 16-row strip per block; wave wv owns N-tiles 4wv..4wv+3 ----
    int rowb = blockIdx.x * 16;
    int r0 = lane & 15;                       // A row / C col within tile
    int kg = lane >> 4;                       // k-group (and C row-group)
    int kb = kg * 8;

    short8v afh[4], afl[4];                   // hi/lo A-frags, 4 K-steps
    f32x4 ls = {0.f, 0.f, 0.f, 0.f};          // fp32 logit partials (4 heads)
    f32x4 ld = {0.f, 0.f, 0.f, 0.f};
    #pragma unroll
    for (int ks = 0; ks < 4; ks++) {
        const float* xp = x  + (size_t)(rowb + r0) * 128 + ks * 32 + kb;
        const float* pp = pe + (size_t)((rowb + r0) & (SEQ - 1)) * 128 + ks * 32 + kb;
        float4 xa = *(const float4*)xp;
        float4 xb = *(const float4*)(xp + 4);
        float4 pa = *(const float4*)pp;
        float4 pb = *(const float4*)(pp + 4);
        float v[8];
        v[0] = xa.x * 11.313708499f + pa.x;
        v[1] = xa.y * 11.313708499f + pa.y;
        v[2] = xa.z * 11.313708499f + pa.z;
        v[3] = xa.w * 11.313708499f + pa.w;
        v[4] = xb.x * 11.313708499f + pb.x;
        v[5] = xb.y * 11.313708499f + pb.y;
        v[6] = xb.z * 11.313708499f + pb.z;
        v[7] = xb.w * 11.313708499f + pb.w;
        short8v ah, al;
        #pragma unroll
        for (int j = 0; j < 8; j++) {
            unsigned short hi = f2b(v[j]);
            ah[j] = (short)hi;
            al[j] = (short)f2b(v[j] - bfu(hi));
        }
        afh[ks] = ah; afl[ks] = al;
        if (wv == 0) {                        // fp32 logits (one wave per strip)
            #pragma unroll
            for (int j = 0; j < 8; j++) {
                int k = ks * 32 + kb + j;
                float4 g4 = *(const float4*)(gs + k * 4);
                float4 h4 = *(const float4*)(gd + k * 4);
                ls.x += v[j] * g4.x; ls.y += v[j] * g4.y;
                ls.z += v[j] * g4.z; ls.w += v[j] * g4.w;
                ld.x += v[j] * h4.x; ld.y += v[j] * h4.y;
                ld.z += v[j] * h4.z; ld.w += v[j] * h4.w;
            }
        }
    }
    if (wv == 0) {                            // reduce over the 4 kg lane-groups
        #pragma unroll
        for (int o = 16; o < 64; o <<= 1) {
            ls.x += __shfl_xor(ls.x, o); ls.y += __shfl_xor(ls.y, o);
            ls.z += __shfl_xor(ls.z, o); ls.w += __shfl_xor(ls.w, o);
            ld.x += __shfl_xor(ld.x, o); ld.y += __shfl_xor(ld.y, o);
            ld.z += __shfl_xor(ld.z, o); ld.w += __shfl_xor(ld.w, o);
        }
        if (lane < 16) {
            int row = rowb + lane;
            *(float4*)(as1 + row * 4) = make_float4(ls.x, ls.y, ls.z, ls.w);
            *(float4*)(ad1 + row * 4) = make_float4(ld.x, ld.y, ld.z, ld.w);
        }
    }

    const short8v* wph = (const short8v*)w1hi;
    const short8v* wpl = (const short8v*)w1lo;
    unsigned short* hu = (unsigned short*)h;
    #pragma unroll
    for (int t = 0; t < 4; t++) {
        int n = wv * 4 + t;                   // N-tile (16 cols)
        f32x4 acc = {0.f, 0.f, 0.f, 0.f};
        #pragma unroll
        for (int ks = 0; ks < 4; ks++) {
            short8v bh = wph[(n * 4 + ks) * 64 + lane];
            short8v bl = wpl[(n * 4 + ks) * 64 + lane];
            acc = __builtin_amdgcn_mfma_f32_16x16x32_bf16(afh[ks], bh, acc, 0, 0, 0);
            acc = __builtin_amdgcn_mfma_f32_16x16x32_bf16(afl[ks], bh, acc, 0, 0, 0);
            acc = __builtin_amdgcn_mfma_f32_16x16x32_bf16(afh[ks], bl, acc, 0, 0, 0);
        }
        #pragma unroll
        for (int r = 0; r < 4; r++)
            hu[(size_t)(rowb + kg * 4 + r) * 256 + n * 16 + r0] = f2b(acc[r]);
    }
}

// ---------------- D2: fused softmax + agg1 + gemm2 (R28 known-good: full-row gather) ----------------
// Phase B wave = NODE, lane = 4 channels (uint2): one 512B wave-load per edge covers
// all 4 heads. Phase A: wave = node, all 4 heads, one float4 as1 gather. No barrier
// before phase B (wave-private LDS). 2-deep edge-pair pipeline.
// NOTE (kernel law, R11/R13): TLP-bound — VGPR must stay < 64.
__global__ __launch_bounds__(256) void k_agg1_gemm2(
        const int* __restrict__ cnt, const int* __restrict__ esrc,
        const float* __restrict__ as1, const float* __restrict__ ad1,
        const bf16* __restrict__ h,
        const float* __restrict__ b1,
        const float* __restrict__ W2,
        const float* __restrict__ a_src2, const float* __restrict__ a_dst2,
        bf16* __restrict__ h2, float* __restrict__ as2, float* __restrict__ ad2) {
    __shared__ float hs[4][256];
    __shared__ int2  st[4][4][64];   // [wave(node)][head][slot] = (s, t*inv); gemm2 aliases as part
    int tid = threadIdx.x, lane = tid & 63, wv = tid >> 6;
    int dbase = blockIdx.x * 4;
    int d = dbase + wv;                               // wave's node
    int deg = min(cnt[d], SLOTS);

    // ---- phase A: all 4 heads' normalized edge weights for the wave's node ----
    {
        int s = esrc[(size_t)d * SLOTS + lane] & (N_NODES - 1);   // tail -> masked idx
        float4 av = *(const float4*)(as1 + (size_t)s * 4);        // one 16B gather
        float4 dv = *(const float4*)(ad1 + (size_t)d * 4);        // uniform
        bool live = lane < deg;
        float t0 = live ? __expf(lrelu(av.x + dv.x) - 40.f) : 0.f;
        float t1 = live ? __expf(lrelu(av.y + dv.y) - 40.f) : 0.f;
        float t2 = live ? __expf(lrelu(av.z + dv.z) - 40.f) : 0.f;
        float t3 = live ? __expf(lrelu(av.w + dv.w) - 40.f) : 0.f;
        float i0 = 1.f / wave_sum(t0);                // den > 0 (self-loop)
        float i1 = 1.f / wave_sum(t1);
        float i2 = 1.f / wave_sum(t2);
        float i3 = 1.f / wave_sum(t3);
        int2 p0; p0.x = s; p0.y = __float_as_int(t0 * i0); st[wv][0][lane] = p0;
        int2 p1; p1.x = s; p1.y = __float_as_int(t1 * i1); st[wv][1][lane] = p1;
        int2 p2; p2.x = s; p2.y = __float_as_int(t2 * i2); st[wv][2][lane] = p2;
        int2 p3; p3.x = s; p3.y = __float_as_int(t3 * i3); st[wv][3][lane] = p3;
    }
    // no barrier: wave reads only st[wv] rows it wrote itself

    // ---- phase B: lane = 4 channels; one uint2 load per edge covers all heads ----
    {
        int hd = lane >> 4;                           // head owning channels 4*lane..+3
        const int4* stp4 = (const int4*)st[wv][hd];   // (s0,t0,s1,t1) per edge pair
        const uint2* hb = (const uint2*)h;            // row s = 64 uint2
        float a0 = 0.f, a1 = 0.f, a2 = 0.f, a3 = 0.f;
        int np = (deg + 1) >> 1;                      // edge pairs; tails t=0
        int4 P = stp4[0];
        uint2 u0 = hb[(size_t)P.x * 64 + lane];
        uint2 u1 = hb[(size_t)P.z * 64 + lane];
        for (int q = 1; q < np; q++) {
            int4 Pn = stp4[q];
            uint2 v0 = hb[(size_t)Pn.x * 64 + lane];
            uint2 v1 = hb[(size_t)Pn.z * 64 + lane];
            float ta = __uint_as_float(P.y), tb = __uint_as_float(P.w);
            a0 += __uint_as_float(u0.x << 16) * ta;
            a1 += __uint_as_float(u0.x & 0xffff0000u) * ta;
            a2 += __uint_as_float(u0.y << 16) * ta;
            a3 += __uint_as_float(u0.y & 0xffff0000u) * ta;
            a0 += __uint_as_float(u1.x << 16) * tb;
            a1 += __uint_as_float(u1.x & 0xffff0000u) * tb;
            a2 += __uint_as_float(u1.y << 16) * tb;
            a3 += __uint_as_float(u1.y & 0xffff0000u) * tb;
            P = Pn; u0 = v0; u1 = v1;
        }
        float ta = __uint_as_float(P.y), tb = __uint_as_float(P.w);
        a0 += __uint_as_float(u0.x << 16) * ta;
        a1 += __uint_as_float(u0.x & 0xffff0000u) * ta;
        a2 += __uint_as_float(u0.y << 16) * ta;
        a3 += __uint_as_float(u0.y & 0xffff0000u) * ta;
        a0 += __uint_as_float(u1.x << 16) * tb;
        a1 += __uint_as_float(u1.x & 0xffff0000u) * tb;
        a2 += __uint_as_float(u1.y << 16) * tb;
        a3 += __uint_as_float(u1.y & 0xffff0000u) * tb;

        float4 bb = *(const float4*)(b1 + lane * 4);
        float o0 = a0 + bb.x, o1 = a1 + bb.y, o2 = a2 + bb.z, o3 = a3 + bb.w;
        o0 = o0 > 0.f ? o0 : (__expf(o0) - 1.f);      // elu
        o1 = o1 > 0.f ? o1 : (__expf(o1) - 1.f);
        o2 = o2 > 0.f ? o2 : (__expf(o2) - 1.f);
        o3 = o3 > 0.f ? o3 : (__expf(o3) - 1.f);
        *(float4*)&hs[wv][lane * 4] = make_float4(o0, o1, o2, o3);   // full-wave store
    }
    __syncthreads();   // hs complete; st dead from here -> reuse as part

    float* part = (float*)st;   // 4 KB of the 8 KB st buffer

    // ---- gemm2 on the 4 rows in LDS, K-split across the 4 waves ----
    {
        float acc2[4] = {0, 0, 0, 0};
        const int k4base = wv * 16;
        for (int kk = 0; kk < 16; kk++) {
            int k4 = k4base + kk;
            const float* wp = W2 + (size_t)k4 * 256 + lane;   // W2[(k4*4+q)*64 + lane]
            float w0 = wp[0], w1 = wp[64], w2 = wp[128], w3 = wp[192];
            #pragma unroll
            for (int r = 0; r < 4; r++) {
                float4 u = *(const float4*)&hs[r][k4 * 4];    // wave-uniform -> broadcast
                acc2[r] += u.x * w0 + u.y * w1 + u.z * w2 + u.w * w3;
            }
        }
        #pragma unroll
        for (int r = 0; r < 4; r++) part[(wv * 4 + r) * 64 + lane] = acc2[r];
    }
    __syncthreads();
    {
        int r = wv;                                   // one row per wave
        float a0 = part[(0 * 4 + r) * 64 + lane] + part[(1 * 4 + r) * 64 + lane]
                 + part[(2 * 4 + r) * 64 + lane] + part[(3 * 4 + r) * 64 + lane];
        float asj = a_src2[lane], adj = a_dst2[lane];
        int n0 = dbase + r;
        h2[(size_t)n0 * 64 + lane] = __float2bfloat16(a0);
        float va0 = wave_sum(a0 * asj);
        float vd0 = wave_sum(a0 * adj);
        if (lane == 0) {
            as2[n0] = va0; ad2[n0] = vd0;
        }
    }
}

// ---------------- D3: fused softmax + agg2 -> out (R29: quad gather) ----------------
// R29: lane-group g = lane>>4 handles edge 4q+g; lane = 4 channels via uint2. One
// 512B wave-load covers 4 edges (was 1 edge / 128B). Serial iterations drop ~4x
// (avg deg 17 -> ~5). Epilogue: 2-step shfl_xor cross-group reduce + float4 write.
__global__ __launch_bounds__(256) void k_agg2(const int* __restrict__ cnt,
                                              const int* __restrict__ esrc,
                                              const float* __restrict__ as2,
                                              const float* __restrict__ ad2,
                                              const bf16* __restrict__ h2,
                                              const float* __restrict__ b2v,
                                              float* __restrict__ out) {
    __shared__ int2 sts2[4][64];
    int tid = threadIdx.x, lane = tid & 63, wv = tid >> 6;
    int d = blockIdx.x * 4 + wv;
    int deg = min(cnt[d], SLOTS);

    // phase A: per-edge normalized weights (lane = slot)
    {
        int s = esrc[(size_t)d * SLOTS + lane] & (N_NODES - 1);
        float av = as2[s];
        float adw = ad2[d];
        float t = (lane < deg) ? __expf(lrelu(av + adw) - 40.f) : 0.f;
        float inv = 1.f / wave_sum(t);
        int2 pr; pr.x = s; pr.y = __float_as_int(t * inv);
        sts2[wv][lane] = pr;
    }
    // no barrier: wave reads only its own row

    // phase B: group g handles edges 4q+g; lane = channels (lane&15)*4..+3
    int g = lane >> 4;
    int c16 = lane & 15;
    const uint2* hb2 = (const uint2*)h2;              // row = 16 uint2 (128B)
    float a0 = 0.f, a1 = 0.f, a2 = 0.f, a3 = 0.f;
    int nq = (deg + 3) >> 2;                          // quad iterations; tails t=0
    int2 P = sts2[wv][g];
    uint2 u = hb2[(size_t)P.x * 16 + c16];
    for (int q = 1; q < nq; q++) {
        int2 Pn = sts2[wv][4 * q + g];
        uint2 un = hb2[(size_t)Pn.x * 16 + c16];
        float t = __int_as_float(P.y);
        a0 += __uint_as_float(u.x << 16) * t;
        a1 += __uint_as_float(u.x & 0xffff0000u) * t;
        a2 += __uint_as_float(u.y << 16) * t;
        a3 += __uint_as_float(u.y & 0xffff0000u) * t;
        P = Pn; u = un;
    }
    {
        float t = __int_as_float(P.y);
        a0 += __uint_as_float(u.x << 16) * t;
        a1 += __uint_as_float(u.x & 0xffff0000u) * t;
        a2 += __uint_as_float(u.y << 16) * t;
        a3 += __uint_as_float(u.y & 0xffff0000u) * t;
    }
    // cross-group reduce (4 groups)
    #pragma unroll
    for (int o = 16; o < 64; o <<= 1) {
        a0 += __shfl_xor(a0, o);
        a1 += __shfl_xor(a1, o);
        a2 += __shfl_xor(a2, o);
        a3 += __shfl_xor(a3, o);
    }
    if (lane < 16) {
        float4 bb = *(const float4*)(b2v + c16 * 4);
        float4* dst = (float4*)(out + (size_t)d * 64 + c16 * 4);
        *dst = make_float4(a0 + bb.x, a1 + bb.y, a2 + bb.z, a3 + bb.w);
    }
}

extern "C" void kernel_launch(void* const* d_in, const int* in_sizes, int n_in,
                              void* d_out, int out_size, void* d_ws, size_t ws_size,
                              hipStream_t stream) {
    const float* x    = (const float*)d_in[0];
    const int*   ei   = (const int*)  d_in[1];
    const float* pe   = (const float*)d_in[2];
    const float* W1   = (const float*)d_in[3];
    const float* a_s1 = (const float*)d_in[4];
    const float* a_d1 = (const float*)d_in[5];
    const float* b1   = (const float*)d_in[6];
    const float* W2   = (const float*)d_in[7];
    const float* a_s2 = (const float*)d_in[8];
    const float* a_d2 = (const float*)d_in[9];
    const float* b2   = (const float*)d_in[10];

    const int E    = in_sizes[1] / 2;
    const int n    = N_NODES;
    const int Etot = E + n;

    // workspace carve-up (256B aligned) — footprint ~14.8 MB
    char* p = (char*)d_ws;
    auto alloc = [&](size_t bytes) -> void* {
        void* r = (void*)p;
        p += (bytes + 255) & ~(size_t)255;
        return r;
    };
    int*   cnt     = (int*)  alloc((size_t)n * 4);
    int*   esrc    = (int*)  alloc((size_t)n * SLOTS * 4);
    bf16*  h       = (bf16*) alloc((size_t)n * F1 * 2);
    float* as1     = (float*)alloc((size_t)n * HEADS * 4);
    float* ad1     = (float*)alloc((size_t)n * HEADS * 4);
    bf16*  h2      = (bf16*) alloc((size_t)n * HID * 2);
    float* as2     = (float*)alloc((size_t)n * 4);
    float* ad2     = (float*)alloc((size_t)n * 4);
    unsigned short* w1hi = (unsigned short*)alloc((size_t)D_IN * F1 * 2);   // 64 KB
    unsigned short* w1lo = (unsigned short*)alloc((size_t)D_IN * F1 * 2);   // 64 KB
    float* gs      = (float*)alloc((size_t)D_IN * HEADS * 4);               // 2 KB
    float* gd      = (float*)alloc((size_t)D_IN * HEADS * 4);               // 2 KB

    k_prep      <<<128, 256, 0, stream>>>(W1, a_s1, a_d1, w1hi, w1lo, gs, gd, cnt);
    k_gemm1m    <<<n / 16, 256, 0, stream>>>(x, pe, w1hi, w1lo, gs, gd, h, as1, ad1,
                                             ei, E, Etot, cnt, esrc);
    k_agg1_gemm2<<<n / 4, 256, 0, stream>>>(cnt, esrc, as1, ad1, h, b1,
                                            W2, a_s2, a_d2, h2, as2, ad2);
    k_agg2      <<<n / 4, 256, 0, stream>>>(cnt, esrc, as2, ad2, h2, b2, (float*)d_out);
}

// Round 18
// 150.128 us; speedup vs baseline: 2.2990x; 1.0313x over previous
//
#include <hip/hip_runtime.h>
#include <hip/hip_bf16.h>

typedef __hip_bfloat16 bf16;
typedef __attribute__((ext_vector_type(8))) short short8v;   // 8 bf16 in 4 VGPR
typedef __attribute__((ext_vector_type(4))) float f32x4;

#define N_NODES 16384
#define D_IN    128
#define HID     64
#define HEADS   4
#define F1      256   // HEADS*HID
#define SEQ     128
#define SLOTS   64    // fixed CSR capacity per node (P(deg>64) ~ 1e-12 for this graph)

__device__ __forceinline__ float wave_sum(float v) {
    #pragma unroll
    for (int o = 32; o > 0; o >>= 1) v += __shfl_xor(v, o, 64);
    return v;
}
__device__ __forceinline__ float lrelu(float v) { return v > 0.f ? v : 0.2f * v; }
__device__ __forceinline__ float bfu(unsigned short u) {
    return __uint_as_float((unsigned)u << 16);
}
__device__ __forceinline__ unsigned short f2b(float f) {   // fp32 -> bf16 RNE
    unsigned u = __float_as_uint(f);
    return (unsigned short)((u + 0x7fffu + ((u >> 16) & 1u)) >> 16);
}

// FMA 4 channels of one edge: u = uint2 (4 bf16), ti = t as int bits
#define FMA8(u, ti)                                                  \
    do {                                                             \
        float t_ = __int_as_float(ti);                               \
        a0 += __uint_as_float((u).x << 16) * t_;                     \
        a1 += __uint_as_float((u).x & 0xffff0000u) * t_;             \
        a2 += __uint_as_float((u).y << 16) * t_;                     \
        a3 += __uint_as_float((u).y & 0xffff0000u) * t_;             \
    } while (0)

// ---------------- D0: prep — W1 hi/lo bf16 split in MFMA B-frag order, g = W1·a, cnt=0 ----------------
// (R27 known-good)
__global__ __launch_bounds__(256) void k_prep(const float* __restrict__ W1,
                                              const float* __restrict__ a_s1,
                                              const float* __restrict__ a_d1,
                                              unsigned short* __restrict__ w1hi,
                                              unsigned short* __restrict__ w1lo,
                                              float* __restrict__ gs,
                                              float* __restrict__ gd,
                                              int* __restrict__ cnt) {
    int gid = blockIdx.x * 256 + threadIdx.x;
    int j  = gid & 7;
    int l  = (gid >> 3) & 63;
    int ks = (gid >> 9) & 3;
    int n  = gid >> 11;
    int k   = ks * 32 + ((l >> 4) << 3) + j;
    int col = n * 16 + (l & 15);
    float w = W1[(size_t)k * 256 + col];
    unsigned short hi = f2b(w);
    w1hi[gid] = hi;
    w1lo[gid] = f2b(w - bfu(hi));
    if (gid < N_NODES) cnt[gid] = 0;
    if (gid < 512) {
        int kk = gid >> 2, hd = gid & 3;
        const float* wr = W1 + (size_t)kk * 256 + hd * 64;
        const float* as = a_s1 + hd * 64;
        const float* ad = a_d1 + hd * 64;
        float s = 0.f, d2 = 0.f;
        for (int c = 0; c < 64; c++) { float wv = wr[c]; s += wv * as[c]; d2 += wv * ad[c]; }
        gs[gid] = s; gd[gid] = d2;
    }
}

// ---------------- D1: scatter + MFMA gemm1 (+PE, +fp32 logits) (R29 known-good) ----------------
// KERNEL LAW (R12): launch_bounds 2nd arg REQUIRED — pins VGPR <= 128.
__global__ __launch_bounds__(256, 4) void k_gemm1m(const float* __restrict__ x,
                                                   const float* __restrict__ pe,
                                                   const unsigned short* __restrict__ w1hi,
                                                   const unsigned short* __restrict__ w1lo,
                                                   const float* __restrict__ gs,
                                                   const float* __restrict__ gd,
                                                   bf16* __restrict__ h,
                                                   float* __restrict__ as1,
                                                   float* __restrict__ ad1,
                                                   const int* __restrict__ ei, int E, int Etot,
                                                   int* __restrict__ cnt,
                                                   int* __restrict__ esrc) {
    int tid = threadIdx.x, lane = tid & 63, wv = tid >> 6;

    // ---- phase 0: edge scatter (grid-stride over 262144 threads) ----
    for (int e = blockIdx.x * 256 + tid; e < Etot; e += 262144) {
        int s, d;
        if (e < E) { s = ei[e]; d = ei[E + e]; }
        else       { s = e - E; d = s; }
        int pos = atomicAdd(&cnt[d], 1);
        if (pos < SLOTS) esrc[d * SLOTS + pos] = s;
    }

    // ---- gemm phase: one 16-row strip per block; wave wv owns N-tiles 4wv..4wv+3 ----
    int rowb = blockIdx.x * 16;
    int r0 = lane & 15;                       // A row / C col within tile
    int kg = lane >> 4;                       // k-group (and C row-group)
    int kb = kg * 8;

    short8v afh[4], afl[4];                   // hi/lo A-frags, 4 K-steps
    f32x4 ls = {0.f, 0.f, 0.f, 0.f};          // fp32 logit partials (4 heads)
    f32x4 ld = {0.f, 0.f, 0.f, 0.f};
    #pragma unroll
    for (int ks = 0; ks < 4; ks++) {
        const float* xp = x  + (size_t)(rowb + r0) * 128 + ks * 32 + kb;
        const float* pp = pe + (size_t)((rowb + r0) & (SEQ - 1)) * 128 + ks * 32 + kb;
        float4 xa = *(const float4*)xp;
        float4 xb = *(const float4*)(xp + 4);
        float4 pa = *(const float4*)pp;
        float4 pb = *(const float4*)(pp + 4);
        float v[8];
        v[0] = xa.x * 11.313708499f + pa.x;
        v[1] = xa.y * 11.313708499f + pa.y;
        v[2] = xa.z * 11.313708499f + pa.z;
        v[3] = xa.w * 11.313708499f + pa.w;
        v[4] = xb.x * 11.313708499f + pb.x;
        v[5] = xb.y * 11.313708499f + pb.y;
        v[6] = xb.z * 11.313708499f + pb.z;
        v[7] = xb.w * 11.313708499f + pb.w;
        short8v ah, al;
        #pragma unroll
        for (int j = 0; j < 8; j++) {
            unsigned short hi = f2b(v[j]);
            ah[j] = (short)hi;
            al[j] = (short)f2b(v[j] - bfu(hi));
        }
        afh[ks] = ah; afl[ks] = al;
        if (wv == 0) {                        // fp32 logits (one wave per strip)
            #pragma unroll
            for (int j = 0; j < 8; j++) {
                int k = ks * 32 + kb + j;
                float4 g4 = *(const float4*)(gs + k * 4);
                float4 h4 = *(const float4*)(gd + k * 4);
                ls.x += v[j] * g4.x; ls.y += v[j] * g4.y;
                ls.z += v[j] * g4.z; ls.w += v[j] * g4.w;
                ld.x += v[j] * h4.x; ld.y += v[j] * h4.y;
                ld.z += v[j] * h4.z; ld.w += v[j] * h4.w;
            }
        }
    }
    if (wv == 0) {                            // reduce over the 4 kg lane-groups
        #pragma unroll
        for (int o = 16; o < 64; o <<= 1) {
            ls.x += __shfl_xor(ls.x, o); ls.y += __shfl_xor(ls.y, o);
            ls.z += __shfl_xor(ls.z, o); ls.w += __shfl_xor(ls.w, o);
            ld.x += __shfl_xor(ld.x, o); ld.y += __shfl_xor(ld.y, o);
            ld.z += __shfl_xor(ld.z, o); ld.w += __shfl_xor(ld.w, o);
        }
        if (lane < 16) {
            int row = rowb + lane;
            *(float4*)(as1 + row * 4) = make_float4(ls.x, ls.y, ls.z, ls.w);
            *(float4*)(ad1 + row * 4) = make_float4(ld.x, ld.y, ld.z, ld.w);
        }
    }

    const short8v* wph = (const short8v*)w1hi;
    const short8v* wpl = (const short8v*)w1lo;
    unsigned short* hu = (unsigned short*)h;
    #pragma unroll
    for (int t = 0; t < 4; t++) {
        int n = wv * 4 + t;                   // N-tile (16 cols)
        f32x4 acc = {0.f, 0.f, 0.f, 0.f};
        #pragma unroll
        for (int ks = 0; ks < 4; ks++) {
            short8v bh = wph[(n * 4 + ks) * 64 + lane];
            short8v bl = wpl[(n * 4 + ks) * 64 + lane];
            acc = __builtin_amdgcn_mfma_f32_16x16x32_bf16(afh[ks], bh, acc, 0, 0, 0);
            acc = __builtin_amdgcn_mfma_f32_16x16x32_bf16(afl[ks], bh, acc, 0, 0, 0);
            acc = __builtin_amdgcn_mfma_f32_16x16x32_bf16(afh[ks], bl, acc, 0, 0, 0);
        }
        #pragma unroll
        for (int r = 0; r < 4; r++)
            hu[(size_t)(rowb + kg * 4 + r) * 256 + n * 16 + r0] = f2b(acc[r]);
    }
}

// ---------------- D2: fused softmax + agg1 + gemm2 (R30: head-overlap + 2-pair pipeline) ----------------
// R30 (single change this round, for clean attribution): (1) the first 4 h-row
// loads depend only on s — issue them (via 4 shfls) BEFORE the as1 gather + exp +
// 4 wave_sum butterflies, hiding ~700cy of phase-A serial work under the gathers.
// (2) main loop processes 2 pairs/iter with the next 2 pairs in flight (4 loads
// deep, was 2). Tail slots have t=0 + masked-valid s, so padded pairs are
// semantics-preserving. VGPR est ~55 (<64 kernel law).
__global__ __launch_bounds__(256) void k_agg1_gemm2(
        const int* __restrict__ cnt, const int* __restrict__ esrc,
        const float* __restrict__ as1, const float* __restrict__ ad1,
        const bf16* __restrict__ h,
        const float* __restrict__ b1,
        const float* __restrict__ W2,
        const float* __restrict__ a_src2, const float* __restrict__ a_dst2,
        bf16* __restrict__ h2, float* __restrict__ as2, float* __restrict__ ad2) {
    __shared__ float hs[4][256];
    __shared__ int2  st[4][4][64];   // [wave(node)][head][slot] = (s, t*inv); gemm2 aliases as part
    int tid = threadIdx.x, lane = tid & 63, wv = tid >> 6;
    int dbase = blockIdx.x * 4;
    int d = dbase + wv;                               // wave's node
    int deg = min(cnt[d], SLOTS);
    const uint2* hb = (const uint2*)h;                // row s = 64 uint2 (512B)

    // ---- phase A with early-issued first-4-edge h-loads ----
    uint2 eu0, eu1, eu2, eu3;
    {
        int s = esrc[(size_t)d * SLOTS + lane] & (N_NODES - 1);   // tail -> masked idx
        // early h-loads for edges 0..3 (addresses need only s; fly under the softmax)
        int s0 = __shfl(s, 0), s1 = __shfl(s, 1), s2 = __shfl(s, 2), s3 = __shfl(s, 3);
        eu0 = hb[(size_t)s0 * 64 + lane];
        eu1 = hb[(size_t)s1 * 64 + lane];
        eu2 = hb[(size_t)s2 * 64 + lane];
        eu3 = hb[(size_t)s3 * 64 + lane];

        float4 av = *(const float4*)(as1 + (size_t)s * 4);        // one 16B gather
        float4 dv = *(const float4*)(ad1 + (size_t)d * 4);        // uniform
        bool live = lane < deg;
        float t0 = live ? __expf(lrelu(av.x + dv.x) - 40.f) : 0.f;
        float t1 = live ? __expf(lrelu(av.y + dv.y) - 40.f) : 0.f;
        float t2 = live ? __expf(lrelu(av.z + dv.z) - 40.f) : 0.f;
        float t3 = live ? __expf(lrelu(av.w + dv.w) - 40.f) : 0.f;
        float i0 = 1.f / wave_sum(t0);                // den > 0 (self-loop)
        float i1 = 1.f / wave_sum(t1);
        float i2 = 1.f / wave_sum(t2);
        float i3 = 1.f / wave_sum(t3);
        int2 p0; p0.x = s; p0.y = __float_as_int(t0 * i0); st[wv][0][lane] = p0;
        int2 p1; p1.x = s; p1.y = __float_as_int(t1 * i1); st[wv][1][lane] = p1;
        int2 p2; p2.x = s; p2.y = __float_as_int(t2 * i2); st[wv][2][lane] = p2;
        int2 p3; p3.x = s; p3.y = __float_as_int(t3 * i3); st[wv][3][lane] = p3;
    }
    // no barrier: wave reads only st[wv] rows it wrote itself

    // ---- phase B: lane = 4 channels; 2-pair-deep pipelined edge loop ----
    {
        int hd = lane >> 4;                           // head owning channels 4*lane..+3
        const int4* stp4 = (const int4*)st[wv][hd];   // (s0,t0,s1,t1) per edge pair
        float a0 = 0.f, a1 = 0.f, a2 = 0.f, a3 = 0.f;
        int np = (deg + 1) >> 1;                      // pairs; tails t=0 (safe to pad)

        int4 P0 = stp4[0];                            // t's for preloaded edges 0..3
        int4 P1 = stp4[1];
        int4 P2 = stp4[2];                            // prefetch pairs 2,3
        int4 P3 = stp4[3];
        uint2 w20 = hb[(size_t)P2.x * 64 + lane];
        uint2 w21 = hb[(size_t)P2.z * 64 + lane];
        uint2 w30 = hb[(size_t)P3.x * 64 + lane];
        uint2 w31 = hb[(size_t)P3.z * 64 + lane];
        FMA8(eu0, P0.y);                              // edges 0..3 (preloaded in A)
        FMA8(eu1, P0.w);
        FMA8(eu2, P1.y);
        FMA8(eu3, P1.w);
        for (int q = 4; q < np; q += 2) {             // q even, q+1 <= 31 (np <= 32)
            int4 N0 = stp4[q];
            int4 N1 = stp4[q + 1];
            uint2 x20 = hb[(size_t)N0.x * 64 + lane];
            uint2 x21 = hb[(size_t)N0.z * 64 + lane];
            uint2 x30 = hb[(size_t)N1.x * 64 + lane];
            uint2 x31 = hb[(size_t)N1.z * 64 + lane];
            FMA8(w20, P2.y);                          // pairs currently held
            FMA8(w21, P2.w);
            FMA8(w30, P3.y);
            FMA8(w31, P3.w);
            P2 = N0; P3 = N1;
            w20 = x20; w21 = x21; w30 = x30; w31 = x31;
        }
        FMA8(w20, P2.y);                              // last held pairs (t=0 if padded)
        FMA8(w21, P2.w);
        FMA8(w30, P3.y);
        FMA8(w31, P3.w);

        float4 bb = *(const float4*)(b1 + lane * 4);
        float o0 = a0 + bb.x, o1 = a1 + bb.y, o2 = a2 + bb.z, o3 = a3 + bb.w;
        o0 = o0 > 0.f ? o0 : (__expf(o0) - 1.f);      // elu
        o1 = o1 > 0.f ? o1 : (__expf(o1) - 1.f);
        o2 = o2 > 0.f ? o2 : (__expf(o2) - 1.f);
        o3 = o3 > 0.f ? o3 : (__expf(o3) - 1.f);
        *(float4*)&hs[wv][lane * 4] = make_float4(o0, o1, o2, o3);   // full-wave store
    }
    __syncthreads();   // hs complete; st dead from here -> reuse as part

    float* part = (float*)st;   // 4 KB of the 8 KB st buffer

    // ---- gemm2 on the 4 rows in LDS, K-split across the 4 waves ----
    {
        float acc2[4] = {0, 0, 0, 0};
        const int k4base = wv * 16;
        for (int kk = 0; kk < 16; kk++) {
            int k4 = k4base + kk;
            const float* wp = W2 + (size_t)k4 * 256 + lane;   // W2[(k4*4+q)*64 + lane]
            float w0 = wp[0], w1 = wp[64], w2 = wp[128], w3 = wp[192];
            #pragma unroll
            for (int r = 0; r < 4; r++) {
                float4 u = *(const float4*)&hs[r][k4 * 4];    // wave-uniform -> broadcast
                acc2[r] += u.x * w0 + u.y * w1 + u.z * w2 + u.w * w3;
            }
        }
        #pragma unroll
        for (int r = 0; r < 4; r++) part[(wv * 4 + r) * 64 + lane] = acc2[r];
    }
    __syncthreads();
    {
        int r = wv;                                   // one row per wave
        float a0 = part[(0 * 4 + r) * 64 + lane] + part[(1 * 4 + r) * 64 + lane]
                 + part[(2 * 4 + r) * 64 + lane] + part[(3 * 4 + r) * 64 + lane];
        float asj = a_src2[lane], adj = a_dst2[lane];
        int n0 = dbase + r;
        h2[(size_t)n0 * 64 + lane] = __float2bfloat16(a0);
        float va0 = wave_sum(a0 * asj);
        float vd0 = wave_sum(a0 * adj);
        if (lane == 0) {
            as2[n0] = va0; ad2[n0] = vd0;
        }
    }
}

// ---------------- D3: fused softmax + agg2 -> out (R29 known-good: quad gather) ----------------
__global__ __launch_bounds__(256) void k_agg2(const int* __restrict__ cnt,
                                              const int* __restrict__ esrc,
                                              const float* __restrict__ as2,
                                              const float* __restrict__ ad2,
                                              const bf16* __restrict__ h2,
                                              const float* __restrict__ b2v,
                                              float* __restrict__ out) {
    __shared__ int2 sts2[4][64];
    int tid = threadIdx.x, lane = tid & 63, wv = tid >> 6;
    int d = blockIdx.x * 4 + wv;
    int deg = min(cnt[d], SLOTS);

    // phase A: per-edge normalized weights (lane = slot)
    {
        int s = esrc[(size_t)d * SLOTS + lane] & (N_NODES - 1);
        float av = as2[s];
        float adw = ad2[d];
        float t = (lane < deg) ? __expf(lrelu(av + adw) - 40.f) : 0.f;
        float inv = 1.f / wave_sum(t);
        int2 pr; pr.x = s; pr.y = __float_as_int(t * inv);
        sts2[wv][lane] = pr;
    }
    // no barrier: wave reads only its own row

    // phase B: group g handles edges 4q+g; lane = channels (lane&15)*4..+3
    int g = lane >> 4;
    int c16 = lane & 15;
    const uint2* hb2 = (const uint2*)h2;              // row = 16 uint2 (128B)
    float a0 = 0.f, a1 = 0.f, a2 = 0.f, a3 = 0.f;
    int nq = (deg + 3) >> 2;                          // quad iterations; tails t=0
    int2 P = sts2[wv][g];
    uint2 u = hb2[(size_t)P.x * 16 + c16];
    for (int q = 1; q < nq; q++) {
        int2 Pn = sts2[wv][4 * q + g];
        uint2 un = hb2[(size_t)Pn.x * 16 + c16];
        float t = __int_as_float(P.y);
        a0 += __uint_as_float(u.x << 16) * t;
        a1 += __uint_as_float(u.x & 0xffff0000u) * t;
        a2 += __uint_as_float(u.y << 16) * t;
        a3 += __uint_as_float(u.y & 0xffff0000u) * t;
        P = Pn; u = un;
    }
    {
        float t = __int_as_float(P.y);
        a0 += __uint_as_float(u.x << 16) * t;
        a1 += __uint_as_float(u.x & 0xffff0000u) * t;
        a2 += __uint_as_float(u.y << 16) * t;
        a3 += __uint_as_float(u.y & 0xffff0000u) * t;
    }
    // cross-group reduce (4 groups)
    #pragma unroll
    for (int o = 16; o < 64; o <<= 1) {
        a0 += __shfl_xor(a0, o);
        a1 += __shfl_xor(a1, o);
        a2 += __shfl_xor(a2, o);
        a3 += __shfl_xor(a3, o);
    }
    if (lane < 16) {
        float4 bb = *(const float4*)(b2v + c16 * 4);
        float4* dst = (float4*)(out + (size_t)d * 64 + c16 * 4);
        *dst = make_float4(a0 + bb.x, a1 + bb.y, a2 + bb.z, a3 + bb.w);
    }
}

extern "C" void kernel_launch(void* const* d_in, const int* in_sizes, int n_in,
                              void* d_out, int out_size, void* d_ws, size_t ws_size,
                              hipStream_t stream) {
    const float* x    = (const float*)d_in[0];
    const int*   ei   = (const int*)  d_in[1];
    const float* pe   = (const float*)d_in[2];
    const float* W1   = (const float*)d_in[3];
    const float* a_s1 = (const float*)d_in[4];
    const float* a_d1 = (const float*)d_in[5];
    const float* b1   = (const float*)d_in[6];
    const float* W2   = (const float*)d_in[7];
    const float* a_s2 = (const float*)d_in[8];
    const float* a_d2 = (const float*)d_in[9];
    const float* b2   = (const float*)d_in[10];

    const int E    = in_sizes[1] / 2;
    const int n    = N_NODES;
    const int Etot = E + n;

    // workspace carve-up (256B aligned) — footprint ~14.8 MB
    char* p = (char*)d_ws;
    auto alloc = [&](size_t bytes) -> void* {
        void* r = (void*)p;
        p += (bytes + 255) & ~(size_t)255;
        return r;
    };
    int*   cnt     = (int*)  alloc((size_t)n * 4);
    int*   esrc    = (int*)  alloc((size_t)n * SLOTS * 4);
    bf16*  h       = (bf16*) alloc((size_t)n * F1 * 2);
    float* as1     = (float*)alloc((size_t)n * HEADS * 4);
    float* ad1     = (float*)alloc((size_t)n * HEADS * 4);
    bf16*  h2      = (bf16*) alloc((size_t)n * HID * 2);
    float* as2     = (float*)alloc((size_t)n * 4);
    float* ad2     = (float*)alloc((size_t)n * 4);
    unsigned short* w1hi = (unsigned short*)alloc((size_t)D_IN * F1 * 2);   // 64 KB
    unsigned short* w1lo = (unsigned short*)alloc((size_t)D_IN * F1 * 2);   // 64 KB
    float* gs      = (float*)alloc((size_t)D_IN * HEADS * 4);               // 2 KB
    float* gd      = (float*)alloc((size_t)D_IN * HEADS * 4);               // 2 KB

    k_prep      <<<128, 256, 0, stream>>>(W1, a_s1, a_d1, w1hi, w1lo, gs, gd, cnt);
    k_gemm1m    <<<n / 16, 256, 0, stream>>>(x, pe, w1hi, w1lo, gs, gd, h, as1, ad1,
                                             ei, E, Etot, cnt, esrc);
    k_agg1_gemm2<<<n / 4, 256, 0, stream>>>(cnt, esrc, as1, ad1, h, b1,
                                            W2, a_s2, a_d2, h2, as2, ad2);
    k_agg2      <<<n / 4, 256, 0, stream>>>(cnt, esrc, as2, ad2, h2, b2, (float*)d_out);
}